// Round 8
// baseline (501.079 us; speedup 1.0000x reference)
//
#include <hip/hip_runtime.h>
#include <hip/hip_bf16.h>
#include <hip/hip_cooperative_groups.h>
#include <math.h>

namespace cg = cooperative_groups;

typedef unsigned short u16;
typedef unsigned int u32;
typedef __bf16 bf16x8 __attribute__((ext_vector_type(8)));
typedef float f32x4 __attribute__((ext_vector_type(4)));

// B=8, T=128, S=512, E=D=512, fp32 in/out. d_out: h_tilde | wc | attn (fp32).
#define OUT_WC   524288LL
#define OUT_ATTN 1048576LL
#define C2 2.8853900817779268f   // 2*log2(e)
#define LOG2E 1.4426950408889634f
#define LAS 40                   // LDS row stride (u16) BK=32: 32 + 8
#define LAS2 72                  // LDS row stride (u16) BK=64: 64 + 8

__device__ inline u16 f2b(float f) {
    return (u16)((__float_as_uint(f) + 0x8000u) >> 16);
}
__device__ inline u32 pkcvt(float x, float y) {
    __hip_bfloat162 h = __float22bfloat162_rn(make_float2(x, y));
    return *(u32*)&h;
}
__device__ inline float tanh_fast(float x) {
    return 1.f - 2.f * __builtin_amdgcn_rcpf(__builtin_amdgcn_exp2f(C2 * x) + 1.f);
}
__device__ inline float wred_sum(float v) {
    #pragma unroll
    for (int i = 32; i > 0; i >>= 1) v += __shfl_xor(v, i);
    return v;
}
__device__ inline float wred_max(float v) {
    #pragma unroll
    for (int i = 32; i > 0; i >>= 1) v = fmaxf(v, __shfl_xor(v, i));
    return v;
}
__device__ inline void proc8(uint4 c, float4 hw, float* a0, float* a1) {
    u32 cc[4] = {c.x, c.y, c.z, c.w};
    #pragma unroll
    for (int i = 0; i < 4; ++i) {
        float xl = __uint_as_float(cc[i] << 16);
        float xh = __uint_as_float(cc[i] & 0xFFFF0000u);
        float rl0 = __builtin_amdgcn_rcpf(fmaf(hw.x, xl, 1.f));
        float rh0 = __builtin_amdgcn_rcpf(fmaf(hw.x, xh, 1.f));
        float rl1 = __builtin_amdgcn_rcpf(fmaf(hw.y, xl, 1.f));
        float rh1 = __builtin_amdgcn_rcpf(fmaf(hw.y, xh, 1.f));
        a0[2*i]   = fmaf(hw.z, rl0, a0[2*i]);
        a0[2*i+1] = fmaf(hw.z, rh0, a0[2*i+1]);
        a1[2*i]   = fmaf(hw.z, rl1, a1[2*i]);
        a1[2*i+1] = fmaf(hw.z, rh1, a1[2*i+1]);
    }
}
__device__ inline void wcproc2(uint4 c, float2 ap, float* q0, float* q1) {
    u32 cc[4] = {c.x, c.y, c.z, c.w};
    #pragma unroll
    for (int i = 0; i < 4; ++i) {
        float el = __uint_as_float(cc[i] << 16);
        float eh = __uint_as_float(cc[i] & 0xFFFF0000u);
        q0[2*i]   = fmaf(ap.x, el, q0[2*i]);
        q0[2*i+1] = fmaf(ap.x, eh, q0[2*i+1]);
        q1[2*i]   = fmaf(ap.y, el, q1[2*i]);
        q1[2*i+1] = fmaf(ap.y, eh, q1[2*i+1]);
    }
}

// ======================= FALLBACK KERNELS (r6, proven 150.8us) ===============
__global__ __launch_bounds__(256) void proj(
    const float* __restrict__ hidden, const float* __restrict__ enc,
    const float* __restrict__ Wattn, const float* __restrict__ battn,
    const float* __restrict__ Wout,
    float* __restrict__ hp, u16* __restrict__ ept, float* __restrict__ hh,
    u16* __restrict__ enc_bf)
{
    __shared__ u16 lA[64 * LAS2];
    __shared__ u16 lB[64 * LAS2];
    const int tid = threadIdx.x;
    const int wvi = tid >> 6, ln = tid & 63;
    const int wm = wvi >> 1, wn = wvi & 1;
    const int l16 = ln & 15, quad = ln >> 4;
    const int blk = blockIdx.x;
    int bx, by, zz = 0, lda, ldb, mode;
    const float *A, *B;
    if (blk < 512) {
        mode = 0; zz = blk >> 6; by = (blk >> 3) & 7; bx = blk & 7;
        A = Wattn + 512; lda = 1024;
        B = enc + (long long)zz * 262144; ldb = 512;
    } else if (blk < 640) {
        mode = 1; int i = blk - 512; by = i >> 3; bx = i & 7;
        A = hidden; lda = 512; B = Wattn; ldb = 1024;
    } else {
        mode = 2; int i = blk - 640; by = i >> 3; bx = i & 7;
        A = hidden; lda = 512; B = Wout + 512; ldb = 1024;
    }
    const int m0 = by * 64, n0 = bx * 64;
    const int srow = tid >> 2, scol = (tid & 3) * 16;
    const float* Ap = A + (long long)(m0 + srow) * lda + scol;
    const float* Bp = B + (long long)(n0 + srow) * ldb + scol;
    const bool wr_enc = (mode == 0) && (by == 0);

    f32x4 acc00 = {0,0,0,0}, acc01 = {0,0,0,0}, acc10 = {0,0,0,0}, acc11 = {0,0,0,0};
    float4 pa0, pa1, pa2, pa3, pb0, pb1, pb2, pb3;
    #define PROJ_LOADK(k0) do { \
        pa0 = *(const float4*)(Ap + (k0));      pa1 = *(const float4*)(Ap + (k0) + 4);  \
        pa2 = *(const float4*)(Ap + (k0) + 8);  pa3 = *(const float4*)(Ap + (k0) + 12); \
        pb0 = *(const float4*)(Bp + (k0));      pb1 = *(const float4*)(Bp + (k0) + 4);  \
        pb2 = *(const float4*)(Bp + (k0) + 8);  pb3 = *(const float4*)(Bp + (k0) + 12); } while (0)
    PROJ_LOADK(0);
    for (int step = 0; step < 8; ++step) {
        uint4 av0 = make_uint4(pkcvt(pa0.x, pa0.y), pkcvt(pa0.z, pa0.w),
                               pkcvt(pa1.x, pa1.y), pkcvt(pa1.z, pa1.w));
        uint4 av1 = make_uint4(pkcvt(pa2.x, pa2.y), pkcvt(pa2.z, pa2.w),
                               pkcvt(pa3.x, pa3.y), pkcvt(pa3.z, pa3.w));
        uint4 bv0 = make_uint4(pkcvt(pb0.x, pb0.y), pkcvt(pb0.z, pb0.w),
                               pkcvt(pb1.x, pb1.y), pkcvt(pb1.z, pb1.w));
        uint4 bv1 = make_uint4(pkcvt(pb2.x, pb2.y), pkcvt(pb2.z, pb2.w),
                               pkcvt(pb3.x, pb3.y), pkcvt(pb3.z, pb3.w));
        if (wr_enc) {
            u16* ed = enc_bf + (long long)zz * 262144 +
                      (long long)(n0 + srow) * 512 + step * 64 + scol;
            *(uint4*)ed = bv0;
            *(uint4*)(ed + 8) = bv1;
        }
        __syncthreads();
        *(uint4*)&lA[srow * LAS2 + scol]     = av0;
        *(uint4*)&lA[srow * LAS2 + scol + 8] = av1;
        *(uint4*)&lB[srow * LAS2 + scol]     = bv0;
        *(uint4*)&lB[srow * LAS2 + scol + 8] = bv1;
        __syncthreads();
        if (step < 7) PROJ_LOADK((step + 1) * 64);
        #pragma unroll
        for (int kh = 0; kh < 2; ++kh) {
            bf16x8 a0 = *(const bf16x8*)&lA[(wm * 32      + l16) * LAS2 + kh * 32 + quad * 8];
            bf16x8 a1 = *(const bf16x8*)&lA[(wm * 32 + 16 + l16) * LAS2 + kh * 32 + quad * 8];
            bf16x8 b0 = *(const bf16x8*)&lB[(wn * 32      + l16) * LAS2 + kh * 32 + quad * 8];
            bf16x8 b1 = *(const bf16x8*)&lB[(wn * 32 + 16 + l16) * LAS2 + kh * 32 + quad * 8];
            acc00 = __builtin_amdgcn_mfma_f32_16x16x32_bf16(a0, b0, acc00, 0, 0, 0);
            acc01 = __builtin_amdgcn_mfma_f32_16x16x32_bf16(a0, b1, acc01, 0, 0, 0);
            acc10 = __builtin_amdgcn_mfma_f32_16x16x32_bf16(a1, b0, acc10, 0, 0, 0);
            acc11 = __builtin_amdgcn_mfma_f32_16x16x32_bf16(a1, b1, acc11, 0, 0, 0);
        }
    }
    #undef PROJ_LOADK
    const f32x4* accs[4] = { &acc00, &acc01, &acc10, &acc11 };
    #pragma unroll
    for (int i = 0; i < 2; ++i) {
        #pragma unroll
        for (int j = 0; j < 2; ++j) {
            const f32x4& a = *accs[i * 2 + j];
            #pragma unroll
            for (int r = 0; r < 4; ++r) {
                int m = m0 + wm * 32 + i * 16 + quad * 4 + r;
                int n = n0 + wn * 32 + j * 16 + l16;
                float v = a[r];
                if (mode == 0)
                    ept[(long long)zz * 262144 + (long long)m * 512 + n] =
                        f2b(__builtin_amdgcn_exp2f(C2 * v));
                else if (mode == 1)
                    hp[(long long)m * 512 + n] = C2 * (v + battn[n]);
                else
                    hh[(long long)m * 512 + n] = v;
            }
        }
    }
}

__global__ __launch_bounds__(1024) void energies(
    const float* __restrict__ maskp, const float* __restrict__ hp,
    const u16* __restrict__ ept, const float* __restrict__ Wv,
    const float* __restrict__ bvp, const u16* __restrict__ enc_bf,
    float* __restrict__ attn, float* __restrict__ wc)
{
    __shared__ __align__(16) float4 hpw[512];
    __shared__ float pa[2][16][512];
    __shared__ float aL[512][2];
    __shared__ float red[16];
    const int tid = threadIdx.x;
    const int b  = blockIdx.x & 7;
    const int t0 = (blockIdx.x >> 3) * 2;
    const int th = tid >> 9;
    const int k5 = tid & 511;
    const long long row0 = (long long)(b * 128 + t0) * 512;

    float hv = hp[row0 + (long long)th * 512 + k5];
    float eh = __builtin_amdgcn_exp2f(hv);
    float* hpwf = (float*)hpw;
    hpwf[k5 * 4 + th] = eh;
    float w = 0.f;
    if (th == 0) { w = Wv[k5]; hpwf[k5 * 4 + 2] = w; }
    float wsum = wred_sum(w);
    if ((tid & 63) == 0) red[tid >> 6] = wsum;
    __syncthreads();
    float sumWv = 0.f;
    #pragma unroll
    for (int i = 0; i < 16; ++i) sumWv += red[i];

    const int kg = tid >> 6, sl = tid & 63;
    const int s0 = sl * 8;
    const u16* eb = ept + (long long)b * 262144 + (kg * 32) * 512 + s0;
    const float4* hq = &hpw[kg * 32];

    float a0[8] = {0,0,0,0,0,0,0,0}, a1[8] = {0,0,0,0,0,0,0,0};
    uint4 c0 = *(const uint4*)(eb);
    uint4 c1 = *(const uint4*)(eb + 512);
    for (int kk = 0; kk < 30; kk += 2) {
        const u16* nb = eb + (kk + 2) * 512;
        uint4 n0 = *(const uint4*)(nb);
        uint4 n1 = *(const uint4*)(nb + 512);
        proc8(c0, hq[kk],     a0, a1);
        proc8(c1, hq[kk + 1], a0, a1);
        c0 = n0; c1 = n1;
    }
    proc8(c0, hq[30], a0, a1);
    proc8(c1, hq[31], a0, a1);

    *(float4*)&pa[0][kg][s0]     = make_float4(a0[0], a0[1], a0[2], a0[3]);
    *(float4*)&pa[0][kg][s0 + 4] = make_float4(a0[4], a0[5], a0[6], a0[7]);
    *(float4*)&pa[1][kg][s0]     = make_float4(a1[0], a1[1], a1[2], a1[3]);
    *(float4*)&pa[1][kg][s0 + 4] = make_float4(a1[4], a1[5], a1[6], a1[7]);
    __syncthreads();

    float A = 0.f;
    #pragma unroll
    for (int g = 0; g < 16; ++g) A += pa[th][g][k5];
    float mv = maskp[(long long)b * 512 + k5];
    float bv0 = bvp[0];
    float r = (bv0 + sumWv - 2.f * A) * mv; r *= mv;

    float vmax = wred_max(r);
    if ((tid & 63) == 0) red[tid >> 6] = vmax;
    __syncthreads();
    float mx = red[th * 8];
    #pragma unroll
    for (int i = 1; i < 8; ++i) mx = fmaxf(mx, red[th * 8 + i]);

    float ex = __builtin_amdgcn_exp2f((r - mx) * LOG2E) * mv;
    float vsum = wred_sum(ex);
    __syncthreads();
    if ((tid & 63) == 0) red[tid >> 6] = vsum;
    __syncthreads();
    float sm = 0.f;
    #pragma unroll
    for (int i = 0; i < 8; ++i) sm += red[th * 8 + i];
    float at = ex * (1.f / (sm + 1e-6f));
    attn[row0 + (long long)th * 512 + k5] = at;
    aL[k5][th] = at;
    __syncthreads();

    const int eg = tid & 63, sg = tid >> 6;
    const u16* encb = enc_bf + (long long)b * 262144 + (long long)(sg * 32) * 512 + eg * 8;
    const float2* aq = (const float2*)&aL[sg * 32][0];
    float q0[8] = {0,0,0,0,0,0,0,0}, q1[8] = {0,0,0,0,0,0,0,0};
    uint4 e0 = *(const uint4*)(encb);
    uint4 e1 = *(const uint4*)(encb + 512);
    for (int j = 0; j < 30; j += 2) {
        uint4 f0 = *(const uint4*)(encb + (long long)(j + 2) * 512);
        uint4 f1 = *(const uint4*)(encb + (long long)(j + 3) * 512);
        wcproc2(e0, aq[j],     q0, q1);
        wcproc2(e1, aq[j + 1], q0, q1);
        e0 = f0; e1 = f1;
    }
    wcproc2(e0, aq[30], q0, q1);
    wcproc2(e1, aq[31], q0, q1);

    *(float4*)&pa[0][sg][eg * 8]     = make_float4(q0[0], q0[1], q0[2], q0[3]);
    *(float4*)&pa[0][sg][eg * 8 + 4] = make_float4(q0[4], q0[5], q0[6], q0[7]);
    *(float4*)&pa[1][sg][eg * 8]     = make_float4(q1[0], q1[1], q1[2], q1[3]);
    *(float4*)&pa[1][sg][eg * 8 + 4] = make_float4(q1[4], q1[5], q1[6], q1[7]);
    __syncthreads();

    float wcv = 0.f;
    #pragma unroll
    for (int g = 0; g < 16; ++g) wcv += pa[th][g][k5];
    wc[row0 + (long long)th * 512 + k5] = wcv;
}

__global__ __launch_bounds__(256) void hout_k(
    const float* __restrict__ wc, const float* __restrict__ Wout,
    float* __restrict__ out)
{
    __shared__ u16 lA[32 * LAS];
    __shared__ u16 lB[64 * LAS];
    const int tid = threadIdx.x;
    const int wvi = tid >> 6, ln = tid & 63;
    const int l16 = ln & 15, quad = ln >> 4;
    const int msub = wvi & 1, npair = wvi >> 1;
    const int m0 = blockIdx.y * 32, n0 = blockIdx.x * 64;
    const int rowA = tid >> 3, kofA = (tid & 7) * 4;
    const int rowB = tid >> 2, kofB = (tid & 3) * 8;
    const float* Apw = wc + (long long)(m0 + rowA) * 512 + kofA;
    const float* Bpw = Wout + (long long)(n0 + rowB) * 1024 + kofB;
    f32x4 acc0 = {0,0,0,0}, acc1 = {0,0,0,0};

    float4 av, bw0, bw1;
    av  = *(const float4*)(Apw);
    bw0 = *(const float4*)(Bpw);
    bw1 = *(const float4*)(Bpw + 4);
    for (int k0 = 0; k0 < 512; k0 += 32) {
        uint2 aw = make_uint2(pkcvt(av.x, av.y), pkcvt(av.z, av.w));
        uint4 bv = make_uint4(pkcvt(bw0.x, bw0.y), pkcvt(bw0.z, bw0.w),
                              pkcvt(bw1.x, bw1.y), pkcvt(bw1.z, bw1.w));
        __syncthreads();
        *(uint2*)&lA[rowA * LAS + kofA] = aw;
        int kk = kofB ^ (((rowB >> 3) & 3) << 3);
        *(uint4*)&lB[rowB * LAS + kk] = bv;
        __syncthreads();
        if (k0 < 480) {
            av  = *(const float4*)(Apw + k0 + 32);
            bw0 = *(const float4*)(Bpw + k0 + 32);
            bw1 = *(const float4*)(Bpw + k0 + 36);
        }
        bf16x8 a = *(const bf16x8*)&lA[(msub * 16 + l16) * LAS + quad * 8];
        int nr0 = npair * 32 + l16, nr1 = nr0 + 16;
        bf16x8 b0 = *(const bf16x8*)&lB[nr0 * LAS + (quad * 8 ^ (((nr0 >> 3) & 3) << 3))];
        bf16x8 b1 = *(const bf16x8*)&lB[nr1 * LAS + (quad * 8 ^ (((nr1 >> 3) & 3) << 3))];
        acc0 = __builtin_amdgcn_mfma_f32_16x16x32_bf16(a, b0, acc0, 0, 0, 0);
        acc1 = __builtin_amdgcn_mfma_f32_16x16x32_bf16(a, b1, acc1, 0, 0, 0);
    }
    #pragma unroll
    for (int j = 0; j < 2; ++j) {
        const f32x4& a = j ? acc1 : acc0;
        #pragma unroll
        for (int r = 0; r < 4; ++r) {
            int m = m0 + msub * 16 + quad * 4 + r;
            int n = n0 + npair * 32 + j * 16 + l16;
            long long idx = (long long)m * 512 + n;
            out[idx] = tanh_fast(a[r] + out[idx]);
        }
    }
}

// ======================= FUSED COOPERATIVE KERNEL ============================
// 256 blocks x 1024 threads: 1 block/CU -- the trivially-satisfiable coop
// capacity (r7 at 512 blocks never launched; return value was unchecked).
// Phase1: 3 x 64x64 GEMM tiles/block (768 total). Phase2: r4-proven dual-t
// energies body, 2 t-pairs sequentially. Phase3: hout on bid<128.
// ept/enc_bf producer & consumer XCD-aligned (zz = b = bid&7).

// one 64x64xK=512 tile with 1024 threads (16 waves, 1 frag each), BK=64
__device__ __forceinline__ void gemm_task(
    int tsk, const float* __restrict__ hidden, const float* __restrict__ enc,
    const float* __restrict__ Wattn, const float* __restrict__ battn,
    const float* __restrict__ Wout, float* __restrict__ hp,
    u16* __restrict__ ept, u16* __restrict__ enc_bf,
    const float* __restrict__ wcp, float* __restrict__ outp,
    u16* lA, u16* lB, int tid)
{
    int mode, bx, by, zz = 0, lda, ldb;
    const float *A, *B;
    if (tsk < 512) {
        mode = 0; zz = tsk >> 6; by = (tsk >> 3) & 7; bx = tsk & 7;
        A = Wattn + 512; lda = 1024;
        B = enc + (long long)zz * 262144; ldb = 512;
    } else if (tsk < 640) {
        mode = 1; int i = tsk - 512; by = i >> 3; bx = i & 7;
        A = hidden; lda = 512; B = Wattn; ldb = 1024;
    } else if (tsk < 768) {
        mode = 2; int i = tsk - 640; by = i >> 3; bx = i & 7;
        A = hidden; lda = 512; B = Wout + 512; ldb = 1024;
    } else {
        mode = 3; int i = tsk - 768; by = i >> 3; bx = i & 7;
        A = wcp; lda = 512; B = Wout; ldb = 1024;
    }
    const int m0 = by * 64, n0 = bx * 64;
    const int srow = tid >> 4, sc = (tid & 15) * 4;   // 16 thr/row, 4 f32 each
    const int wvi = tid >> 6, ln = tid & 63;
    const int wm = wvi >> 2, wn = wvi & 3;            // 4x4 wave grid, 16x16 frag
    const int l16 = ln & 15, quad = ln >> 4;
    const float* Ap = A + (long long)(m0 + srow) * lda + sc;
    const float* Bp = B + (long long)(n0 + srow) * ldb + sc;
    const bool wr_enc = (mode == 0) && (by == 0);

    f32x4 acc = {0,0,0,0};
    float4 qa = *(const float4*)(Ap);
    float4 qb = *(const float4*)(Bp);
    for (int step = 0; step < 8; ++step) {
        uint2 av = make_uint2(pkcvt(qa.x, qa.y), pkcvt(qa.z, qa.w));
        uint2 bv = make_uint2(pkcvt(qb.x, qb.y), pkcvt(qb.z, qb.w));
        if (wr_enc)
            *(uint2*)(enc_bf + (long long)zz * 262144 +
                      (long long)(n0 + srow) * 512 + step * 64 + sc) = bv;
        __syncthreads();
        *(uint2*)&lA[srow * LAS2 + sc] = av;
        *(uint2*)&lB[srow * LAS2 + sc] = bv;
        __syncthreads();
        if (step < 7) {
            qa = *(const float4*)(Ap + (step + 1) * 64);
            qb = *(const float4*)(Bp + (step + 1) * 64);
        }
        #pragma unroll
        for (int kh = 0; kh < 2; ++kh) {
            bf16x8 a = *(const bf16x8*)&lA[(wm * 16 + l16) * LAS2 + kh * 32 + quad * 8];
            bf16x8 b = *(const bf16x8*)&lB[(wn * 16 + l16) * LAS2 + kh * 32 + quad * 8];
            acc = __builtin_amdgcn_mfma_f32_16x16x32_bf16(a, b, acc, 0, 0, 0);
        }
    }
    #pragma unroll
    for (int r = 0; r < 4; ++r) {
        int m = m0 + wm * 16 + quad * 4 + r;
        int n = n0 + wn * 16 + l16;
        float v = acc[r];
        long long idx = (long long)m * 512 + n;
        if (mode == 0)
            ept[(long long)zz * 262144 + idx] = f2b(__builtin_amdgcn_exp2f(C2 * v));
        else if (mode == 1)
            hp[idx] = C2 * (v + battn[n]);
        else if (mode == 2)
            outp[idx] = v;
        else
            outp[idx] = tanh_fast(v + outp[idx]);   // outp holds hh
    }
}

__global__ __launch_bounds__(1024) void fused(
    const float* __restrict__ hidden, const float* __restrict__ enc,
    const float* __restrict__ maskp, const float* __restrict__ Wattn,
    const float* __restrict__ battn, const float* __restrict__ Wv,
    const float* __restrict__ bvp, const float* __restrict__ Wout,
    float* __restrict__ out, float* __restrict__ hp,
    u16* __restrict__ ept, u16* __restrict__ enc_bf)
{
    __shared__ __align__(16) char smem[77888];
    u16* lA = (u16*)smem;                     // phase 1/3: 9216 B
    u16* lB = (u16*)(smem + 9216);            // phase 1/3: 9216 B
    const int tid = threadIdx.x;
    const int bid = blockIdx.x;
    float* wcp   = out + OUT_WC;
    float* attnp = out + OUT_ATTN;
    cg::grid_group grid = cg::this_grid();

    // -------- phase 1: proj (3 tiles per block; mode0 XCD-aligned) --------
    {
        int t1 = ((bid & 7) << 6) | (bid >> 3);   // zz = bid&7, by 0..3
        gemm_task(t1,        hidden, enc, Wattn, battn, Wout, hp, ept, enc_bf, wcp, out, lA, lB, tid);
        gemm_task(t1 + 32,   hidden, enc, Wattn, battn, Wout, hp, ept, enc_bf, wcp, out, lA, lB, tid);
        gemm_task(512 + bid, hidden, enc, Wattn, battn, Wout, hp, ept, enc_bf, wcp, out, lA, lB, tid);
    }
    __threadfence();
    grid.sync();
    __threadfence();

    // -------- phase 2: energies + softmax + wc, 2 t-pair units --------
    {
        float4* hpw = (float4*)smem;                               // 8KB
        float (*pa)[16][512] = (float (*)[16][512])(smem + 8192);  // 64KB
        float (*aL)[2] = (float (*)[2])(smem + 73728);             // 4KB
        float* red = (float*)(smem + 77824);                       // 64B
        const int b = bid & 7;                 // matches phase-1 zz (same XCD)
        const int th = tid >> 9, k5 = tid & 511;
        const int kg = tid >> 6, sl = tid & 63;
        const int s0 = sl * 8;
        const float mv = maskp[(long long)b * 512 + k5];
        const float bv0 = bvp[0];

        for (int u = 0; u < 2; ++u) {
            const int t0 = (((bid >> 3) << 1) | u) * 2;
            const long long row0 = (long long)(b * 128 + t0) * 512;

            float hv = hp[row0 + (long long)th * 512 + k5];
            float ehv = __builtin_amdgcn_exp2f(hv);
            float* hpwf = (float*)hpw;
            hpwf[k5 * 4 + th] = ehv;
            float w = 0.f;
            if (th == 0) { w = Wv[k5]; hpwf[k5 * 4 + 2] = w; }
            float wsum = wred_sum(w);
            if ((tid & 63) == 0) red[tid >> 6] = wsum;
            __syncthreads();
            float sumWv = 0.f;
            #pragma unroll
            for (int i = 0; i < 16; ++i) sumWv += red[i];

            const u16* eb = ept + (long long)b * 262144 + (kg * 32) * 512 + s0;
            const float4* hq = &hpw[kg * 32];
            float a0[8] = {0,0,0,0,0,0,0,0}, a1[8] = {0,0,0,0,0,0,0,0};
            uint4 c0 = *(const uint4*)(eb);
            uint4 c1 = *(const uint4*)(eb + 512);
            for (int kk = 0; kk < 30; kk += 2) {
                const u16* nb = eb + (kk + 2) * 512;
                uint4 n0v = *(const uint4*)(nb);
                uint4 n1v = *(const uint4*)(nb + 512);
                proc8(c0, hq[kk],     a0, a1);
                proc8(c1, hq[kk + 1], a0, a1);
                c0 = n0v; c1 = n1v;
            }
            proc8(c0, hq[30], a0, a1);
            proc8(c1, hq[31], a0, a1);

            *(float4*)&pa[0][kg][s0]     = make_float4(a0[0], a0[1], a0[2], a0[3]);
            *(float4*)&pa[0][kg][s0 + 4] = make_float4(a0[4], a0[5], a0[6], a0[7]);
            *(float4*)&pa[1][kg][s0]     = make_float4(a1[0], a1[1], a1[2], a1[3]);
            *(float4*)&pa[1][kg][s0 + 4] = make_float4(a1[4], a1[5], a1[6], a1[7]);
            __syncthreads();

            float A = 0.f;
            #pragma unroll
            for (int g = 0; g < 16; ++g) A += pa[th][g][k5];
            float r = (bv0 + sumWv - 2.f * A) * mv; r *= mv;

            float vmax = wred_max(r);
            if ((tid & 63) == 0) red[tid >> 6] = vmax;
            __syncthreads();
            float mx = red[th * 8];
            #pragma unroll
            for (int i = 1; i < 8; ++i) mx = fmaxf(mx, red[th * 8 + i]);

            float ex = __builtin_amdgcn_exp2f((r - mx) * LOG2E) * mv;
            float vsum = wred_sum(ex);
            __syncthreads();
            if ((tid & 63) == 0) red[tid >> 6] = vsum;
            __syncthreads();
            float sm = 0.f;
            #pragma unroll
            for (int i = 0; i < 8; ++i) sm += red[th * 8 + i];
            float at = ex * (1.f / (sm + 1e-6f));
            attnp[row0 + (long long)th * 512 + k5] = at;
            aL[k5][th] = at;
            __syncthreads();

            const int eg = tid & 63, sg = tid >> 6;
            const u16* encb = enc_bf + (long long)b * 262144 +
                              (long long)(sg * 32) * 512 + eg * 8;
            const float2* aq = (const float2*)&aL[sg * 32][0];
            float q0[8] = {0,0,0,0,0,0,0,0}, q1[8] = {0,0,0,0,0,0,0,0};
            uint4 e0 = *(const uint4*)(encb);
            uint4 e1 = *(const uint4*)(encb + 512);
            for (int j = 0; j < 30; j += 2) {
                uint4 f0 = *(const uint4*)(encb + (long long)(j + 2) * 512);
                uint4 f1 = *(const uint4*)(encb + (long long)(j + 3) * 512);
                wcproc2(e0, aq[j],     q0, q1);
                wcproc2(e1, aq[j + 1], q0, q1);
                e0 = f0; e1 = f1;
            }
            wcproc2(e0, aq[30], q0, q1);
            wcproc2(e1, aq[31], q0, q1);

            *(float4*)&pa[0][sg][eg * 8]     = make_float4(q0[0], q0[1], q0[2], q0[3]);
            *(float4*)&pa[0][sg][eg * 8 + 4] = make_float4(q0[4], q0[5], q0[6], q0[7]);
            *(float4*)&pa[1][sg][eg * 8]     = make_float4(q1[0], q1[1], q1[2], q1[3]);
            *(float4*)&pa[1][sg][eg * 8 + 4] = make_float4(q1[4], q1[5], q1[6], q1[7]);
            __syncthreads();

            float wcv = 0.f;
            #pragma unroll
            for (int g = 0; g < 16; ++g) wcv += pa[th][g][k5];
            wcp[row0 + (long long)th * 512 + k5] = wcv;
            __syncthreads();   // protect pa/red reuse by next unit
        }
    }
    __threadfence();
    grid.sync();
    __threadfence();

    // -------- phase 3: hout (128 tiles) --------
    if (bid < 128)
        gemm_task(768 + bid, hidden, enc, Wattn, battn, Wout, hp, ept, enc_bf,
                  wcp, out, lA, lB, tid);
}

extern "C" void kernel_launch(void* const* d_in, const int* in_sizes, int n_in,
                              void* d_out, int out_size, void* d_ws, size_t ws_size,
                              hipStream_t stream)
{
    const float* hidden = (const float*)d_in[0];  // (8,128,512)
    const float* enc    = (const float*)d_in[1];  // (8,512,512)
    const float* mask   = (const float*)d_in[2];  // (8,512)
    const float* Wattn  = (const float*)d_in[3];  // (512,1024)
    const float* battn  = (const float*)d_in[4];  // (512,)
    const float* Wv     = (const float*)d_in[5];  // (512,)
    const float* bvp    = (const float*)d_in[6];  // (1,)
    const float* Wout   = (const float*)d_in[7];  // (512,1024)
    float* out = (float*)d_out;

    float* hp     = (float*)d_ws;                     // @0   2MB fp32
    u16*   ept    = (u16*)((char*)d_ws + (2 << 20));  // @2M  4MB bf16 (exp2 domain)
    u16*   enc_bf = (u16*)((char*)d_ws + (6 << 20));  // @6M  4MB bf16

    void* kargs[] = { (void*)&hidden, (void*)&enc, (void*)&mask, (void*)&Wattn,
                      (void*)&battn, (void*)&Wv, (void*)&bvp, (void*)&Wout,
                      (void*)&out, (void*)&hp, (void*)&ept, (void*)&enc_bf };
    hipError_t cerr = hipLaunchCooperativeKernel((const void*)fused, dim3(256),
                                                 dim3(1024), kargs, 0, stream);
    if (cerr != hipSuccess) {
        (void)hipGetLastError();   // clear sticky error, use proven 3-kernel path
        proj<<<768, 256, 0, stream>>>(hidden, enc, Wattn, battn, Wout,
                                      hp, ept, out /* hh in-place */, enc_bf);
        energies<<<512, 1024, 0, stream>>>(mask, hp, ept, Wv, bvp, enc_bf,
                                           out + OUT_ATTN, out + OUT_WC);
        hout_k<<<dim3(8, 32, 1), 256, 0, stream>>>(out + OUT_WC, Wout, out);
    }
}

// Round 9
// 147.247 us; speedup vs baseline: 3.4030x; 3.4030x over previous
//
#include <hip/hip_runtime.h>
#include <hip/hip_bf16.h>
#include <math.h>

typedef unsigned short u16;
typedef unsigned int u32;
typedef __bf16 bf16x8 __attribute__((ext_vector_type(8)));
typedef float f32x4 __attribute__((ext_vector_type(4)));

// B=8, T=128, S=512, E=D=512, fp32 in/out. d_out: h_tilde | wc | attn (fp32).
#define OUT_WC   524288LL
#define OUT_ATTN 1048576LL
#define C2 2.8853900817779268f   // 2*log2(e)
#define LOG2E 1.4426950408889634f
#define LAS 40                   // LDS row stride (u16): 32 + 8 pad

__device__ inline u16 f2b(float f) {
    return (u16)((__float_as_uint(f) + 0x8000u) >> 16);
}
__device__ inline u32 pkcvt(float x, float y) {
    __hip_bfloat162 h = __float22bfloat162_rn(make_float2(x, y));
    return *(u32*)&h;
}
__device__ inline float tanh_fast(float x) {
    return 1.f - 2.f * __builtin_amdgcn_rcpf(__builtin_amdgcn_exp2f(C2 * x) + 1.f);
}

// =============== tobf: fp32 -> bf16 pre-convert (enc|hidden|Wattn|Wout) ======
__global__ __launch_bounds__(256) void tobf(
    const float* __restrict__ enc, const float* __restrict__ hidden,
    const float* __restrict__ Wattn, const float* __restrict__ Wout,
    u16* __restrict__ dst)
{
    long long i = ((long long)blockIdx.x * 256 + threadIdx.x) * 8;
    const float* src; long long off;
    if (i < 2097152)      { src = enc;    off = i; }
    else if (i < 2621440) { src = hidden; off = i - 2097152; }
    else if (i < 3145728) { src = Wattn;  off = i - 2621440; }
    else                  { src = Wout;   off = i - 3145728; }
    float4 v0 = *(const float4*)(src + off);
    float4 v1 = *(const float4*)(src + off + 4);
    *(uint4*)(dst + i) = make_uint4(pkcvt(v0.x, v0.y), pkcvt(v0.z, v0.w),
                                    pkcvt(v1.x, v1.y), pkcvt(v1.z, v1.w));
}

// =============== proj: ept + hp + hh fused, 768 blocks, 64x64 tiles ==========
// (r4 verbatim -- the configuration that produced the 146.6us best)
__global__ __launch_bounds__(256) void proj(
    const u16* __restrict__ hidden_bf, const u16* __restrict__ enc_bf,
    const u16* __restrict__ Wattn_bf, const float* __restrict__ battn,
    const u16* __restrict__ Wout_bf,
    float* __restrict__ hp, u16* __restrict__ ept, float* __restrict__ hh)
{
    __shared__ u16 lA[64 * LAS];
    __shared__ u16 lB[64 * LAS];
    const int tid = threadIdx.x;
    const int wvi = tid >> 6, ln = tid & 63;
    const int wm = wvi >> 1, wn = wvi & 1;
    const int l16 = ln & 15, quad = ln >> 4;
    const int blk = blockIdx.x;
    int bx, by, zz = 0, lda, ldb, mode;
    const u16 *A, *B;
    if (blk < 512) {
        mode = 0;
        zz = blk >> 6; by = (blk >> 3) & 7; bx = blk & 7;
        A = Wattn_bf + 512; lda = 1024;
        B = enc_bf + (long long)zz * 262144; ldb = 512;
    } else if (blk < 640) {
        mode = 1;
        int i = blk - 512; by = i >> 3; bx = i & 7;
        A = hidden_bf; lda = 512;
        B = Wattn_bf; ldb = 1024;
    } else {
        mode = 2;
        int i = blk - 640; by = i >> 3; bx = i & 7;
        A = hidden_bf; lda = 512;
        B = Wout_bf + 512; ldb = 1024;
    }
    const int m0 = by * 64, n0 = bx * 64;
    const int srow = tid >> 2, skof = (tid & 3) * 8;
    const u16* Ap = A + (long long)(m0 + srow) * lda + skof;
    const u16* Bp = B + (long long)(n0 + srow) * ldb + skof;

    f32x4 acc00 = {0,0,0,0}, acc01 = {0,0,0,0}, acc10 = {0,0,0,0}, acc11 = {0,0,0,0};

    for (int k0 = 0; k0 < 512; k0 += 32) {
        uint4 av = *(const uint4*)(Ap + k0);
        uint4 bv = *(const uint4*)(Bp + k0);
        __syncthreads();
        *(uint4*)&lA[srow * LAS + skof] = av;
        *(uint4*)&lB[srow * LAS + skof] = bv;
        __syncthreads();
        bf16x8 a0 = *(const bf16x8*)&lA[(wm * 32      + l16) * LAS + quad * 8];
        bf16x8 a1 = *(const bf16x8*)&lA[(wm * 32 + 16 + l16) * LAS + quad * 8];
        bf16x8 b0 = *(const bf16x8*)&lB[(wn * 32      + l16) * LAS + quad * 8];
        bf16x8 b1 = *(const bf16x8*)&lB[(wn * 32 + 16 + l16) * LAS + quad * 8];
        acc00 = __builtin_amdgcn_mfma_f32_16x16x32_bf16(a0, b0, acc00, 0, 0, 0);
        acc01 = __builtin_amdgcn_mfma_f32_16x16x32_bf16(a0, b1, acc01, 0, 0, 0);
        acc10 = __builtin_amdgcn_mfma_f32_16x16x32_bf16(a1, b0, acc10, 0, 0, 0);
        acc11 = __builtin_amdgcn_mfma_f32_16x16x32_bf16(a1, b1, acc11, 0, 0, 0);
    }

    const f32x4* accs[4] = { &acc00, &acc01, &acc10, &acc11 };
    #pragma unroll
    for (int i = 0; i < 2; ++i) {
        #pragma unroll
        for (int j = 0; j < 2; ++j) {
            const f32x4& a = *accs[i * 2 + j];
            #pragma unroll
            for (int r = 0; r < 4; ++r) {
                int m = m0 + wm * 32 + i * 16 + quad * 4 + r;
                int n = n0 + wn * 32 + j * 16 + l16;
                float v = a[r];
                if (mode == 0)
                    ept[(long long)zz * 262144 + (long long)m * 512 + n] =
                        f2b(__builtin_amdgcn_exp2f(C2 * v));
                else if (mode == 1)
                    hp[(long long)m * 512 + n] = C2 * (v + battn[n]);
                else
                    hh[(long long)m * 512 + n] = v;
            }
        }
    }
}

// =============== wave reductions ============================================
__device__ inline float wred_sum(float v) {
    #pragma unroll
    for (int i = 32; i > 0; i >>= 1) v += __shfl_xor(v, i);
    return v;
}
__device__ inline float wred_max(float v) {
    #pragma unroll
    for (int i = 32; i > 0; i >>= 1) v = fmaxf(v, __shfl_xor(v, i));
    return v;
}

// =============== energies + masked softmax + wc (fused, dual-t) ==============
// r4 body verbatim; grid split into two 256-block dispatches (toff = t-pair
// offset) purely to drop per-dispatch dur below proj's so the rocprof top-5
// finally exposes proj/hout/tobf. r4's 512-block launch ran as 2 sequential
// 256-block waves anyway (1 block/CU), so the split is ~free.
__device__ inline void proc8(uint4 c, float4 hw, float* a0, float* a1) {
    u32 cc[4] = {c.x, c.y, c.z, c.w};
    #pragma unroll
    for (int i = 0; i < 4; ++i) {
        float xl = __uint_as_float(cc[i] << 16);
        float xh = __uint_as_float(cc[i] & 0xFFFF0000u);
        float rl0 = __builtin_amdgcn_rcpf(fmaf(hw.x, xl, 1.f));
        float rh0 = __builtin_amdgcn_rcpf(fmaf(hw.x, xh, 1.f));
        float rl1 = __builtin_amdgcn_rcpf(fmaf(hw.y, xl, 1.f));
        float rh1 = __builtin_amdgcn_rcpf(fmaf(hw.y, xh, 1.f));
        a0[2*i]   = fmaf(hw.z, rl0, a0[2*i]);
        a0[2*i+1] = fmaf(hw.z, rh0, a0[2*i+1]);
        a1[2*i]   = fmaf(hw.z, rl1, a1[2*i]);
        a1[2*i+1] = fmaf(hw.z, rh1, a1[2*i+1]);
    }
}
__device__ inline void wcproc2(uint4 c, float2 ap, float* acc0, float* acc1) {
    u32 cc[4] = {c.x, c.y, c.z, c.w};
    #pragma unroll
    for (int i = 0; i < 4; ++i) {
        float el = __uint_as_float(cc[i] << 16);
        float eh = __uint_as_float(cc[i] & 0xFFFF0000u);
        acc0[2*i]   = fmaf(ap.x, el, acc0[2*i]);
        acc0[2*i+1] = fmaf(ap.x, eh, acc0[2*i+1]);
        acc1[2*i]   = fmaf(ap.y, el, acc1[2*i]);
        acc1[2*i+1] = fmaf(ap.y, eh, acc1[2*i+1]);
    }
}

__global__ __launch_bounds__(1024) void energies(
    const float* __restrict__ maskp, const float* __restrict__ hp,
    const u16* __restrict__ ept, const float* __restrict__ Wv,
    const float* __restrict__ bvp, const u16* __restrict__ enc_bf,
    float* __restrict__ attn, float* __restrict__ wc, int toff)
{
    __shared__ __align__(16) float4 hpw[512];   // (e^{2hp_t0}, e^{2hp_t1}, Wv, -) 8KB
    __shared__ float pa[2][16][512];            // 64KB partials; reused for wc
    __shared__ float aL[512][2];                // 4KB attn weights for wc
    __shared__ float red[16];
    const int tid = threadIdx.x;
    const int b  = blockIdx.x & 7;              // XCD-grouped
    const int t0 = ((blockIdx.x >> 3) + toff) * 2;
    const int th = tid >> 9;                    // 0: waves 0-7 (t0), 1: waves 8-15 (t0+1)
    const int k5 = tid & 511;
    const long long row0 = (long long)(b * 128 + t0) * 512;

    // ---- setup: hpw + sumWv ----
    float hv = hp[row0 + (long long)th * 512 + k5];
    float eh = __builtin_amdgcn_exp2f(hv);
    float* hpwf = (float*)hpw;
    hpwf[k5 * 4 + th] = eh;
    float w = 0.f;
    if (th == 0) { w = Wv[k5]; hpwf[k5 * 4 + 2] = w; }
    float wsum = wred_sum(w);
    if ((tid & 63) == 0) red[tid >> 6] = wsum;  // th==1 waves write 0: harmless
    __syncthreads();                            // hpw + red visible
    float sumWv = 0.f;
    #pragma unroll
    for (int i = 0; i < 16; ++i) sumWv += red[i];

    // ---- main loop: A[s] = sum_k Wv_k / (e^{2hp}*e^{2ep} + 1), both t ----
    const int kg = tid >> 6, sl = tid & 63;     // kg = wave: 32 k-rows; 8 s-cols
    const int s0 = sl * 8;
    const u16* eb = ept + (long long)b * 262144 + (kg * 32) * 512 + s0;
    const float4* hq = &hpw[kg * 32];

    float a0[8] = {0,0,0,0,0,0,0,0}, a1[8] = {0,0,0,0,0,0,0,0};
    uint4 c0 = *(const uint4*)(eb);
    uint4 c1 = *(const uint4*)(eb + 512);
    for (int kk = 0; kk < 30; kk += 2) {
        const u16* nb = eb + (kk + 2) * 512;
        uint4 n0 = *(const uint4*)(nb);
        uint4 n1 = *(const uint4*)(nb + 512);
        proc8(c0, hq[kk],     a0, a1);
        proc8(c1, hq[kk + 1], a0, a1);
        c0 = n0; c1 = n1;
    }
    proc8(c0, hq[30], a0, a1);
    proc8(c1, hq[31], a0, a1);

    *(float4*)&pa[0][kg][s0]     = make_float4(a0[0], a0[1], a0[2], a0[3]);
    *(float4*)&pa[0][kg][s0 + 4] = make_float4(a0[4], a0[5], a0[6], a0[7]);
    *(float4*)&pa[1][kg][s0]     = make_float4(a1[0], a1[1], a1[2], a1[3]);
    *(float4*)&pa[1][kg][s0 + 4] = make_float4(a1[4], a1[5], a1[6], a1[7]);
    __syncthreads();

    // ---- softmax: thread owns (t = th, s = k5); each wave is one th ----
    float A = 0.f;
    #pragma unroll
    for (int g = 0; g < 16; ++g) A += pa[th][g][k5];   // stride-1 lanes
    float mv = maskp[(long long)b * 512 + k5];
    float bv0 = bvp[0];
    float r = (bv0 + sumWv - 2.f * A) * mv; r *= mv;

    float vmax = wred_max(r);
    if ((tid & 63) == 0) red[tid >> 6] = vmax;  // sumWv reads were pre-barrier
    __syncthreads();
    float mx = red[th * 8];
    #pragma unroll
    for (int i = 1; i < 8; ++i) mx = fmaxf(mx, red[th * 8 + i]);

    float ex = __builtin_amdgcn_exp2f((r - mx) * LOG2E) * mv;
    float vsum = wred_sum(ex);
    __syncthreads();                            // mx reads done before red reuse
    if ((tid & 63) == 0) red[tid >> 6] = vsum;
    __syncthreads();
    float sm = 0.f;
    #pragma unroll
    for (int i = 0; i < 8; ++i) sm += red[th * 8 + i];
    float at = ex * (1.f / (sm + 1e-6f));
    attn[row0 + (long long)th * 512 + k5] = at;
    aL[k5][th] = at;
    __syncthreads();                            // aL visible; pa free for reuse

    // ---- wc = attn @ enc: thread owns 8 e-cols (eg) x 32 s-rows (sg) ----
    const int eg = tid & 63, sg = tid >> 6;
    const u16* encb = enc_bf + (long long)b * 262144 + (long long)(sg * 32) * 512 + eg * 8;
    const float2* aq = (const float2*)&aL[sg * 32][0];
    float acc0[8] = {0,0,0,0,0,0,0,0}, acc1[8] = {0,0,0,0,0,0,0,0};
    uint4 e0 = *(const uint4*)(encb);
    uint4 e1 = *(const uint4*)(encb + 512);
    for (int j = 0; j < 30; j += 2) {
        uint4 f0 = *(const uint4*)(encb + (long long)(j + 2) * 512);
        uint4 f1 = *(const uint4*)(encb + (long long)(j + 3) * 512);
        wcproc2(e0, aq[j],     acc0, acc1);
        wcproc2(e1, aq[j + 1], acc0, acc1);
        e0 = f0; e1 = f1;
    }
    wcproc2(e0, aq[30], acc0, acc1);
    wcproc2(e1, aq[31], acc0, acc1);

    *(float4*)&pa[0][sg][eg * 8]     = make_float4(acc0[0], acc0[1], acc0[2], acc0[3]);
    *(float4*)&pa[0][sg][eg * 8 + 4] = make_float4(acc0[4], acc0[5], acc0[6], acc0[7]);
    *(float4*)&pa[1][sg][eg * 8]     = make_float4(acc1[0], acc1[1], acc1[2], acc1[3]);
    *(float4*)&pa[1][sg][eg * 8 + 4] = make_float4(acc1[4], acc1[5], acc1[6], acc1[7]);
    __syncthreads();

    float wcv = 0.f;
    #pragma unroll
    for (int g = 0; g < 16; ++g) wcv += pa[th][g][k5];
    wc[row0 + (long long)th * 512 + k5] = wcv;
}

// =============== hout: h_tilde = tanh(wc @ Wout[:,:512]^T + hh) ==============
__global__ __launch_bounds__(256) void hout_k(
    const float* __restrict__ wc, const u16* __restrict__ Wout_bf,
    float* __restrict__ out)
{
    __shared__ u16 lA[32 * LAS];
    __shared__ u16 lB[64 * LAS];
    const int tid = threadIdx.x;
    const int wvi = tid >> 6, ln = tid & 63;
    const int l16 = ln & 15, quad = ln >> 4;
    const int msub = wvi & 1, npair = wvi >> 1;
    const int m0 = blockIdx.y * 32, n0 = blockIdx.x * 64;
    const int rowA = tid >> 3, kofA = (tid & 7) * 4;
    const int rowB = tid >> 2, kofB = (tid & 3) * 8;
    f32x4 acc0 = {0,0,0,0}, acc1 = {0,0,0,0};

    for (int k0 = 0; k0 < 512; k0 += 32) {
        float4 av = *(const float4*)(wc + (long long)(m0 + rowA) * 512 + k0 + kofA);
        uint4 bv = *(const uint4*)(Wout_bf + (long long)(n0 + rowB) * 1024 + k0 + kofB);
        __syncthreads();
        *(uint2*)&lA[rowA * LAS + kofA] = make_uint2(pkcvt(av.x, av.y), pkcvt(av.z, av.w));
        int kk = kofB ^ (((rowB >> 3) & 3) << 3);
        *(uint4*)&lB[rowB * LAS + kk] = bv;
        __syncthreads();
        bf16x8 a = *(const bf16x8*)&lA[(msub * 16 + l16) * LAS + quad * 8];
        int nr0 = npair * 32 + l16, nr1 = nr0 + 16;
        bf16x8 b0 = *(const bf16x8*)&lB[nr0 * LAS + (quad * 8 ^ (((nr0 >> 3) & 3) << 3))];
        bf16x8 b1 = *(const bf16x8*)&lB[nr1 * LAS + (quad * 8 ^ (((nr1 >> 3) & 3) << 3))];
        acc0 = __builtin_amdgcn_mfma_f32_16x16x32_bf16(a, b0, acc0, 0, 0, 0);
        acc1 = __builtin_amdgcn_mfma_f32_16x16x32_bf16(a, b1, acc1, 0, 0, 0);
    }
    #pragma unroll
    for (int j = 0; j < 2; ++j) {
        const f32x4& a = j ? acc1 : acc0;
        #pragma unroll
        for (int r = 0; r < 4; ++r) {
            int m = m0 + msub * 16 + quad * 4 + r;
            int n = n0 + npair * 32 + j * 16 + l16;
            long long idx = (long long)m * 512 + n;
            out[idx] = tanh_fast(a[r] + out[idx]);   // out[idx] holds hh
        }
    }
}

extern "C" void kernel_launch(void* const* d_in, const int* in_sizes, int n_in,
                              void* d_out, int out_size, void* d_ws, size_t ws_size,
                              hipStream_t stream)
{
    const float* hidden = (const float*)d_in[0];  // (8,128,512)
    const float* enc    = (const float*)d_in[1];  // (8,512,512)
    const float* mask   = (const float*)d_in[2];  // (8,512)
    const float* Wattn  = (const float*)d_in[3];  // (512,1024)
    const float* battn  = (const float*)d_in[4];  // (512,)
    const float* Wv     = (const float*)d_in[5];  // (512,)
    const float* bvp    = (const float*)d_in[6];  // (1,)
    const float* Wout   = (const float*)d_in[7];  // (512,1024)
    float* out = (float*)d_out;

    float* hp  = (float*)d_ws;                      // @0   2MB fp32
    u16*   ept = (u16*)((char*)d_ws + (2 << 20));   // @2M  4MB bf16 (exp2 domain)
    u16*   bfp = (u16*)((char*)d_ws + (6 << 20));   // @6M  7MB bf16 pool
    u16* enc_bf    = bfp;                // 2M elems
    u16* hidden_bf = bfp + 2097152;      // 512K
    u16* Wattn_bf  = bfp + 2621440;      // 512K
    u16* Wout_bf   = bfp + 3145728;      // 512K

    tobf<<<1792, 256, 0, stream>>>(enc, hidden, Wattn, Wout, bfp);
    proj<<<768, 256, 0, stream>>>(hidden_bf, enc_bf, Wattn_bf, battn, Wout_bf,
                                  hp, ept, out /* hh in-place */);
    energies<<<256, 1024, 0, stream>>>(mask, hp, ept, Wv, bvp, enc_bf,
                                       out + OUT_ATTN, out + OUT_WC, 0);
    energies<<<256, 1024, 0, stream>>>(mask, hp, ept, Wv, bvp, enc_bf,
                                       out + OUT_ATTN, out + OUT_WC, 32);
    hout_k<<<dim3(8, 32, 1), 256, 0, stream>>>(out + OUT_WC, Wout_bf, out);
}

// Round 10
// 146.322 us; speedup vs baseline: 3.4245x; 1.0063x over previous
//
#include <hip/hip_runtime.h>
#include <hip/hip_bf16.h>
#include <math.h>

typedef unsigned short u16;
typedef unsigned int u32;
typedef __bf16 bf16x8 __attribute__((ext_vector_type(8)));
typedef float f32x4 __attribute__((ext_vector_type(4)));

// B=8, T=128, S=512, E=D=512, fp32 in/out. d_out: h_tilde | wc | attn (fp32).
#define OUT_WC   524288LL
#define OUT_ATTN 1048576LL
#define C2 2.8853900817779268f   // 2*log2(e)
#define LOG2E 1.4426950408889634f
#define LAS 40                   // LDS row stride (u16): 32 + 8 pad

__device__ inline u16 f2b(float f) {
    return (u16)((__float_as_uint(f) + 0x8000u) >> 16);
}
__device__ inline u32 pkcvt(float x, float y) {
    __hip_bfloat162 h = __float22bfloat162_rn(make_float2(x, y));
    return *(u32*)&h;
}
__device__ inline float tanh_fast(float x) {
    return 1.f - 2.f * __builtin_amdgcn_rcpf(__builtin_amdgcn_exp2f(C2 * x) + 1.f);
}

// =============== tobf: fp32 -> bf16 pre-convert (enc|hidden|Wattn|Wout) ======
__global__ __launch_bounds__(256) void tobf(
    const float* __restrict__ enc, const float* __restrict__ hidden,
    const float* __restrict__ Wattn, const float* __restrict__ Wout,
    u16* __restrict__ dst)
{
    long long i = ((long long)blockIdx.x * 256 + threadIdx.x) * 8;
    const float* src; long long off;
    if (i < 2097152)      { src = enc;    off = i; }
    else if (i < 2621440) { src = hidden; off = i - 2097152; }
    else if (i < 3145728) { src = Wattn;  off = i - 2621440; }
    else                  { src = Wout;   off = i - 3145728; }
    float4 v0 = *(const float4*)(src + off);
    float4 v1 = *(const float4*)(src + off + 4);
    *(uint4*)(dst + i) = make_uint4(pkcvt(v0.x, v0.y), pkcvt(v0.z, v0.w),
                                    pkcvt(v1.x, v1.y), pkcvt(v1.z, v1.w));
}

// =============== proj: ept + hp + hh fused, 768 blocks, 64x64 tiles ==========
__global__ __launch_bounds__(256) void proj(
    const u16* __restrict__ hidden_bf, const u16* __restrict__ enc_bf,
    const u16* __restrict__ Wattn_bf, const float* __restrict__ battn,
    const u16* __restrict__ Wout_bf,
    float* __restrict__ hp, u16* __restrict__ ept, float* __restrict__ hh)
{
    __shared__ u16 lA[64 * LAS];
    __shared__ u16 lB[64 * LAS];
    const int tid = threadIdx.x;
    const int wvi = tid >> 6, ln = tid & 63;
    const int wm = wvi >> 1, wn = wvi & 1;
    const int l16 = ln & 15, quad = ln >> 4;
    const int blk = blockIdx.x;
    int bx, by, zz = 0, lda, ldb, mode;
    const u16 *A, *B;
    if (blk < 512) {
        mode = 0;
        zz = blk >> 6; by = (blk >> 3) & 7; bx = blk & 7;
        A = Wattn_bf + 512; lda = 1024;
        B = enc_bf + (long long)zz * 262144; ldb = 512;
    } else if (blk < 640) {
        mode = 1;
        int i = blk - 512; by = i >> 3; bx = i & 7;
        A = hidden_bf; lda = 512;
        B = Wattn_bf; ldb = 1024;
    } else {
        mode = 2;
        int i = blk - 640; by = i >> 3; bx = i & 7;
        A = hidden_bf; lda = 512;
        B = Wout_bf + 512; ldb = 1024;
    }
    const int m0 = by * 64, n0 = bx * 64;
    const int srow = tid >> 2, skof = (tid & 3) * 8;
    const u16* Ap = A + (long long)(m0 + srow) * lda + skof;
    const u16* Bp = B + (long long)(n0 + srow) * ldb + skof;

    f32x4 acc00 = {0,0,0,0}, acc01 = {0,0,0,0}, acc10 = {0,0,0,0}, acc11 = {0,0,0,0};

    for (int k0 = 0; k0 < 512; k0 += 32) {
        uint4 av = *(const uint4*)(Ap + k0);
        uint4 bv = *(const uint4*)(Bp + k0);
        __syncthreads();
        *(uint4*)&lA[srow * LAS + skof] = av;
        *(uint4*)&lB[srow * LAS + skof] = bv;
        __syncthreads();
        bf16x8 a0 = *(const bf16x8*)&lA[(wm * 32      + l16) * LAS + quad * 8];
        bf16x8 a1 = *(const bf16x8*)&lA[(wm * 32 + 16 + l16) * LAS + quad * 8];
        bf16x8 b0 = *(const bf16x8*)&lB[(wn * 32      + l16) * LAS + quad * 8];
        bf16x8 b1 = *(const bf16x8*)&lB[(wn * 32 + 16 + l16) * LAS + quad * 8];
        acc00 = __builtin_amdgcn_mfma_f32_16x16x32_bf16(a0, b0, acc00, 0, 0, 0);
        acc01 = __builtin_amdgcn_mfma_f32_16x16x32_bf16(a0, b1, acc01, 0, 0, 0);
        acc10 = __builtin_amdgcn_mfma_f32_16x16x32_bf16(a1, b0, acc10, 0, 0, 0);
        acc11 = __builtin_amdgcn_mfma_f32_16x16x32_bf16(a1, b1, acc11, 0, 0, 0);
    }

    const f32x4* accs[4] = { &acc00, &acc01, &acc10, &acc11 };
    #pragma unroll
    for (int i = 0; i < 2; ++i) {
        #pragma unroll
        for (int j = 0; j < 2; ++j) {
            const f32x4& a = *accs[i * 2 + j];
            #pragma unroll
            for (int r = 0; r < 4; ++r) {
                int m = m0 + wm * 32 + i * 16 + quad * 4 + r;
                int n = n0 + wn * 32 + j * 16 + l16;
                float v = a[r];
                if (mode == 0)
                    ept[(long long)zz * 262144 + (long long)m * 512 + n] =
                        f2b(__builtin_amdgcn_exp2f(C2 * v));
                else if (mode == 1)
                    hp[(long long)m * 512 + n] = C2 * (v + battn[n]);
                else
                    hh[(long long)m * 512 + n] = v;
            }
        }
    }
}

// =============== wave reductions ============================================
__device__ inline float wred_sum(float v) {
    #pragma unroll
    for (int i = 32; i > 0; i >>= 1) v += __shfl_xor(v, i);
    return v;
}
__device__ inline float wred_max(float v) {
    #pragma unroll
    for (int i = 32; i > 0; i >>= 1) v = fmaxf(v, __shfl_xor(v, i));
    return v;
}

// =============== energies + masked softmax + wc (fused, dual-t) ==============
// r4 dataflow, but pa halved to 32KB via two-pass cross-wave reduction
// (write a0 -> barrier -> th0 reduce -> barrier -> write a1 -> barrier -> th1
// reduce; same for wc). LDS 78336 -> 45120 B so two 1024-thr blocks/CU can
// co-reside (90KB + runtime reserve << 160KB). b = bid & 7: XCD-grouped.
__device__ inline void proc8(uint4 c, float4 hw, float* a0, float* a1) {
    u32 cc[4] = {c.x, c.y, c.z, c.w};
    #pragma unroll
    for (int i = 0; i < 4; ++i) {
        float xl = __uint_as_float(cc[i] << 16);
        float xh = __uint_as_float(cc[i] & 0xFFFF0000u);
        float rl0 = __builtin_amdgcn_rcpf(fmaf(hw.x, xl, 1.f));
        float rh0 = __builtin_amdgcn_rcpf(fmaf(hw.x, xh, 1.f));
        float rl1 = __builtin_amdgcn_rcpf(fmaf(hw.y, xl, 1.f));
        float rh1 = __builtin_amdgcn_rcpf(fmaf(hw.y, xh, 1.f));
        a0[2*i]   = fmaf(hw.z, rl0, a0[2*i]);
        a0[2*i+1] = fmaf(hw.z, rh0, a0[2*i+1]);
        a1[2*i]   = fmaf(hw.z, rl1, a1[2*i]);
        a1[2*i+1] = fmaf(hw.z, rh1, a1[2*i+1]);
    }
}
__device__ inline void wcproc2(uint4 c, float2 ap, float* acc0, float* acc1) {
    u32 cc[4] = {c.x, c.y, c.z, c.w};
    #pragma unroll
    for (int i = 0; i < 4; ++i) {
        float el = __uint_as_float(cc[i] << 16);
        float eh = __uint_as_float(cc[i] & 0xFFFF0000u);
        acc0[2*i]   = fmaf(ap.x, el, acc0[2*i]);
        acc0[2*i+1] = fmaf(ap.x, eh, acc0[2*i+1]);
        acc1[2*i]   = fmaf(ap.y, el, acc1[2*i]);
        acc1[2*i+1] = fmaf(ap.y, eh, acc1[2*i+1]);
    }
}

__global__ __launch_bounds__(1024) void energies(
    const float* __restrict__ maskp, const float* __restrict__ hp,
    const u16* __restrict__ ept, const float* __restrict__ Wv,
    const float* __restrict__ bvp, const u16* __restrict__ enc_bf,
    float* __restrict__ attn, float* __restrict__ wc)
{
    __shared__ __align__(16) float4 hpw[512];   // (e^{2hp_t0}, e^{2hp_t1}, Wv, -) 8KB
    __shared__ float pa[16][512];               // 32KB partials, two passes; wc reuse
    __shared__ float aL[512][2];                // 4KB attn weights for wc
    __shared__ float red[16];
    const int tid = threadIdx.x;
    const int b  = blockIdx.x & 7;              // XCD-grouped
    const int t0 = (blockIdx.x >> 3) * 2;
    const int th = tid >> 9;                    // 0: waves 0-7 (t0), 1: waves 8-15 (t0+1)
    const int k5 = tid & 511;
    const long long row0 = (long long)(b * 128 + t0) * 512;

    // ---- setup: hpw + sumWv ----
    float hv = hp[row0 + (long long)th * 512 + k5];
    float eh = __builtin_amdgcn_exp2f(hv);
    float* hpwf = (float*)hpw;
    hpwf[k5 * 4 + th] = eh;
    float w = 0.f;
    if (th == 0) { w = Wv[k5]; hpwf[k5 * 4 + 2] = w; }
    float wsum = wred_sum(w);
    if ((tid & 63) == 0) red[tid >> 6] = wsum;  // th==1 waves write 0: harmless
    __syncthreads();                            // hpw + red visible
    float sumWv = 0.f;
    #pragma unroll
    for (int i = 0; i < 16; ++i) sumWv += red[i];

    // ---- main loop: A[s] = sum_k Wv_k / (e^{2hp}*e^{2ep} + 1), both t ----
    const int kg = tid >> 6, sl = tid & 63;     // kg = wave: 32 k-rows; 8 s-cols
    const int s0 = sl * 8;
    const u16* eb = ept + (long long)b * 262144 + (kg * 32) * 512 + s0;
    const float4* hq = &hpw[kg * 32];

    float a0[8] = {0,0,0,0,0,0,0,0}, a1[8] = {0,0,0,0,0,0,0,0};
    uint4 c0 = *(const uint4*)(eb);
    uint4 c1 = *(const uint4*)(eb + 512);
    for (int kk = 0; kk < 30; kk += 2) {
        const u16* nb = eb + (kk + 2) * 512;
        uint4 n0 = *(const uint4*)(nb);
        uint4 n1 = *(const uint4*)(nb + 512);
        proc8(c0, hq[kk],     a0, a1);
        proc8(c1, hq[kk + 1], a0, a1);
        c0 = n0; c1 = n1;
    }
    proc8(c0, hq[30], a0, a1);
    proc8(c1, hq[31], a0, a1);

    // ---- two-pass cross-wave reduction through 32KB pa ----
    *(float4*)&pa[kg][s0]     = make_float4(a0[0], a0[1], a0[2], a0[3]);
    *(float4*)&pa[kg][s0 + 4] = make_float4(a0[4], a0[5], a0[6], a0[7]);
    __syncthreads();
    float A = 0.f;
    if (th == 0) {
        #pragma unroll
        for (int g = 0; g < 16; ++g) A += pa[g][k5];   // stride-1 lanes
    }
    __syncthreads();                            // t0 reads done before overwrite
    *(float4*)&pa[kg][s0]     = make_float4(a1[0], a1[1], a1[2], a1[3]);
    *(float4*)&pa[kg][s0 + 4] = make_float4(a1[4], a1[5], a1[6], a1[7]);
    __syncthreads();
    if (th == 1) {
        #pragma unroll
        for (int g = 0; g < 16; ++g) A += pa[g][k5];
    }

    // ---- softmax: thread owns (t = th, s = k5); each wave is one th ----
    float mv = maskp[(long long)b * 512 + k5];
    float bv0 = bvp[0];
    float r = (bv0 + sumWv - 2.f * A) * mv; r *= mv;

    float vmax = wred_max(r);
    if ((tid & 63) == 0) red[tid >> 6] = vmax;  // sumWv reads were pre-barrier
    __syncthreads();
    float mx = red[th * 8];
    #pragma unroll
    for (int i = 1; i < 8; ++i) mx = fmaxf(mx, red[th * 8 + i]);

    float ex = __builtin_amdgcn_exp2f((r - mx) * LOG2E) * mv;
    float vsum = wred_sum(ex);
    __syncthreads();                            // mx reads done before red reuse
    if ((tid & 63) == 0) red[tid >> 6] = vsum;
    __syncthreads();
    float sm = 0.f;
    #pragma unroll
    for (int i = 0; i < 8; ++i) sm += red[th * 8 + i];
    float at = ex * (1.f / (sm + 1e-6f));
    attn[row0 + (long long)th * 512 + k5] = at;
    aL[k5][th] = at;
    __syncthreads();                            // aL visible; pa free for reuse

    // ---- wc = attn @ enc: thread owns 8 e-cols (eg) x 32 s-rows (sg) ----
    const int eg = tid & 63, sg = tid >> 6;
    const u16* encb = enc_bf + (long long)b * 262144 + (long long)(sg * 32) * 512 + eg * 8;
    const float2* aq = (const float2*)&aL[sg * 32][0];
    float acc0[8] = {0,0,0,0,0,0,0,0}, acc1[8] = {0,0,0,0,0,0,0,0};
    uint4 e0 = *(const uint4*)(encb);
    uint4 e1 = *(const uint4*)(encb + 512);
    for (int j = 0; j < 30; j += 2) {
        uint4 f0 = *(const uint4*)(encb + (long long)(j + 2) * 512);
        uint4 f1 = *(const uint4*)(encb + (long long)(j + 3) * 512);
        wcproc2(e0, aq[j],     acc0, acc1);
        wcproc2(e1, aq[j + 1], acc0, acc1);
        e0 = f0; e1 = f1;
    }
    wcproc2(e0, aq[30], acc0, acc1);
    wcproc2(e1, aq[31], acc0, acc1);

    // ---- two-pass wc reduction through pa ----
    *(float4*)&pa[sg][eg * 8]     = make_float4(acc0[0], acc0[1], acc0[2], acc0[3]);
    *(float4*)&pa[sg][eg * 8 + 4] = make_float4(acc0[4], acc0[5], acc0[6], acc0[7]);
    __syncthreads();
    float wcv = 0.f;
    if (th == 0) {
        #pragma unroll
        for (int g = 0; g < 16; ++g) wcv += pa[g][k5];
    }
    __syncthreads();                            // t0 reads done before overwrite
    *(float4*)&pa[sg][eg * 8]     = make_float4(acc1[0], acc1[1], acc1[2], acc1[3]);
    *(float4*)&pa[sg][eg * 8 + 4] = make_float4(acc1[4], acc1[5], acc1[6], acc1[7]);
    __syncthreads();
    if (th == 1) {
        #pragma unroll
        for (int g = 0; g < 16; ++g) wcv += pa[g][k5];
    }
    wc[row0 + (long long)th * 512 + k5] = wcv;
}

// =============== hout: h_tilde = tanh(wc @ Wout[:,:512]^T + hh) ==============
__global__ __launch_bounds__(256) void hout_k(
    const float* __restrict__ wc, const u16* __restrict__ Wout_bf,
    float* __restrict__ out)
{
    __shared__ u16 lA[32 * LAS];
    __shared__ u16 lB[64 * LAS];
    const int tid = threadIdx.x;
    const int wvi = tid >> 6, ln = tid & 63;
    const int l16 = ln & 15, quad = ln >> 4;
    const int msub = wvi & 1, npair = wvi >> 1;
    const int m0 = blockIdx.y * 32, n0 = blockIdx.x * 64;
    const int rowA = tid >> 3, kofA = (tid & 7) * 4;
    const int rowB = tid >> 2, kofB = (tid & 3) * 8;
    f32x4 acc0 = {0,0,0,0}, acc1 = {0,0,0,0};

    for (int k0 = 0; k0 < 512; k0 += 32) {
        float4 av = *(const float4*)(wc + (long long)(m0 + rowA) * 512 + k0 + kofA);
        uint4 bv = *(const uint4*)(Wout_bf + (long long)(n0 + rowB) * 1024 + k0 + kofB);
        __syncthreads();
        *(uint2*)&lA[rowA * LAS + kofA] = make_uint2(pkcvt(av.x, av.y), pkcvt(av.z, av.w));
        int kk = kofB ^ (((rowB >> 3) & 3) << 3);
        *(uint4*)&lB[rowB * LAS + kk] = bv;
        __syncthreads();
        bf16x8 a = *(const bf16x8*)&lA[(msub * 16 + l16) * LAS + quad * 8];
        int nr0 = npair * 32 + l16, nr1 = nr0 + 16;
        bf16x8 b0 = *(const bf16x8*)&lB[nr0 * LAS + (quad * 8 ^ (((nr0 >> 3) & 3) << 3))];
        bf16x8 b1 = *(const bf16x8*)&lB[nr1 * LAS + (quad * 8 ^ (((nr1 >> 3) & 3) << 3))];
        acc0 = __builtin_amdgcn_mfma_f32_16x16x32_bf16(a, b0, acc0, 0, 0, 0);
        acc1 = __builtin_amdgcn_mfma_f32_16x16x32_bf16(a, b1, acc1, 0, 0, 0);
    }
    #pragma unroll
    for (int j = 0; j < 2; ++j) {
        const f32x4& a = j ? acc1 : acc0;
        #pragma unroll
        for (int r = 0; r < 4; ++r) {
            int m = m0 + msub * 16 + quad * 4 + r;
            int n = n0 + npair * 32 + j * 16 + l16;
            long long idx = (long long)m * 512 + n;
            out[idx] = tanh_fast(a[r] + out[idx]);   // out[idx] holds hh
        }
    }
}

extern "C" void kernel_launch(void* const* d_in, const int* in_sizes, int n_in,
                              void* d_out, int out_size, void* d_ws, size_t ws_size,
                              hipStream_t stream)
{
    const float* hidden = (const float*)d_in[0];  // (8,128,512)
    const float* enc    = (const float*)d_in[1];  // (8,512,512)
    const float* mask   = (const float*)d_in[2];  // (8,512)
    const float* Wattn  = (const float*)d_in[3];  // (512,1024)
    const float* battn  = (const float*)d_in[4];  // (512,)
    const float* Wv     = (const float*)d_in[5];  // (512,)
    const float* bvp    = (const float*)d_in[6];  // (1,)
    const float* Wout   = (const float*)d_in[7];  // (512,1024)
    float* out = (float*)d_out;

    float* hp  = (float*)d_ws;                      // @0   2MB fp32
    u16*   ept = (u16*)((char*)d_ws + (2 << 20));   // @2M  4MB bf16 (exp2 domain)
    u16*   bfp = (u16*)((char*)d_ws + (6 << 20));   // @6M  7MB bf16 pool
    u16* enc_bf    = bfp;                // 2M elems
    u16* hidden_bf = bfp + 2097152;      // 512K
    u16* Wattn_bf  = bfp + 2621440;      // 512K
    u16* Wout_bf   = bfp + 3145728;      // 512K

    tobf<<<1792, 256, 0, stream>>>(enc, hidden, Wattn, Wout, bfp);
    proj<<<768, 256, 0, stream>>>(hidden_bf, enc_bf, Wattn_bf, battn, Wout_bf,
                                  hp, ept, out /* hh in-place */);
    energies<<<512, 1024, 0, stream>>>(mask, hp, ept, Wv, bvp, enc_bf,
                                       out + OUT_ATTN, out + OUT_WC);
    hout_k<<<dim3(8, 32, 1), 256, 0, stream>>>(out + OUT_WC, Wout_bf, out);
}

// Round 11
// 140.067 us; speedup vs baseline: 3.5774x; 1.0447x over previous
//
#include <hip/hip_runtime.h>
#include <hip/hip_bf16.h>
#include <math.h>

typedef unsigned short u16;
typedef unsigned int u32;
typedef __bf16 bf16x8 __attribute__((ext_vector_type(8)));
typedef float f32x4 __attribute__((ext_vector_type(4)));

// B=8, T=128, S=512, E=D=512, fp32 in/out. d_out: h_tilde | wc | attn (fp32).
#define OUT_WC   524288LL
#define OUT_ATTN 1048576LL
#define C2 2.8853900817779268f   // 2*log2(e)
#define LOG2E 1.4426950408889634f
#define LAS 40                   // LDS row stride (u16): 32 + 8 pad

__device__ inline u16 f2b(float f) {
    return (u16)((__float_as_uint(f) + 0x8000u) >> 16);
}
__device__ inline u32 pkcvt(float x, float y) {
    __hip_bfloat162 h = __float22bfloat162_rn(make_float2(x, y));
    return *(u32*)&h;
}
__device__ inline float tanh_fast(float x) {
    return 1.f - 2.f * __builtin_amdgcn_rcpf(__builtin_amdgcn_exp2f(C2 * x) + 1.f);
}

// =============== tobf: fp32 -> bf16 pre-convert (enc|hidden|Wattn|Wout) ======
__global__ __launch_bounds__(256) void tobf(
    const float* __restrict__ enc, const float* __restrict__ hidden,
    const float* __restrict__ Wattn, const float* __restrict__ Wout,
    u16* __restrict__ dst)
{
    long long i = ((long long)blockIdx.x * 256 + threadIdx.x) * 8;
    const float* src; long long off;
    if (i < 2097152)      { src = enc;    off = i; }
    else if (i < 2621440) { src = hidden; off = i - 2097152; }
    else if (i < 3145728) { src = Wattn;  off = i - 2621440; }
    else                  { src = Wout;   off = i - 3145728; }
    float4 v0 = *(const float4*)(src + off);
    float4 v1 = *(const float4*)(src + off + 4);
    *(uint4*)(dst + i) = make_uint4(pkcvt(v0.x, v0.y), pkcvt(v0.z, v0.w),
                                    pkcvt(v1.x, v1.y), pkcvt(v1.z, v1.w));
}

// =============== proj: ept + hp + hh fused, 768 blocks, 64x64 tiles ==========
__global__ __launch_bounds__(256) void proj(
    const u16* __restrict__ hidden_bf, const u16* __restrict__ enc_bf,
    const u16* __restrict__ Wattn_bf, const float* __restrict__ battn,
    const u16* __restrict__ Wout_bf,
    float* __restrict__ hp, u16* __restrict__ ept, float* __restrict__ hh)
{
    __shared__ u16 lA[64 * LAS];
    __shared__ u16 lB[64 * LAS];
    const int tid = threadIdx.x;
    const int wvi = tid >> 6, ln = tid & 63;
    const int wm = wvi >> 1, wn = wvi & 1;
    const int l16 = ln & 15, quad = ln >> 4;
    const int blk = blockIdx.x;
    int bx, by, zz = 0, lda, ldb, mode;
    const u16 *A, *B;
    if (blk < 512) {
        mode = 0;
        zz = blk >> 6; by = (blk >> 3) & 7; bx = blk & 7;
        A = Wattn_bf + 512; lda = 1024;
        B = enc_bf + (long long)zz * 262144; ldb = 512;
    } else if (blk < 640) {
        mode = 1;
        int i = blk - 512; by = i >> 3; bx = i & 7;
        A = hidden_bf; lda = 512;
        B = Wattn_bf; ldb = 1024;
    } else {
        mode = 2;
        int i = blk - 640; by = i >> 3; bx = i & 7;
        A = hidden_bf; lda = 512;
        B = Wout_bf + 512; ldb = 1024;
    }
    const int m0 = by * 64, n0 = bx * 64;
    const int srow = tid >> 2, skof = (tid & 3) * 8;
    const u16* Ap = A + (long long)(m0 + srow) * lda + skof;
    const u16* Bp = B + (long long)(n0 + srow) * ldb + skof;

    f32x4 acc00 = {0,0,0,0}, acc01 = {0,0,0,0}, acc10 = {0,0,0,0}, acc11 = {0,0,0,0};

    for (int k0 = 0; k0 < 512; k0 += 32) {
        uint4 av = *(const uint4*)(Ap + k0);
        uint4 bv = *(const uint4*)(Bp + k0);
        __syncthreads();
        *(uint4*)&lA[srow * LAS + skof] = av;
        *(uint4*)&lB[srow * LAS + skof] = bv;
        __syncthreads();
        bf16x8 a0 = *(const bf16x8*)&lA[(wm * 32      + l16) * LAS + quad * 8];
        bf16x8 a1 = *(const bf16x8*)&lA[(wm * 32 + 16 + l16) * LAS + quad * 8];
        bf16x8 b0 = *(const bf16x8*)&lB[(wn * 32      + l16) * LAS + quad * 8];
        bf16x8 b1 = *(const bf16x8*)&lB[(wn * 32 + 16 + l16) * LAS + quad * 8];
        acc00 = __builtin_amdgcn_mfma_f32_16x16x32_bf16(a0, b0, acc00, 0, 0, 0);
        acc01 = __builtin_amdgcn_mfma_f32_16x16x32_bf16(a0, b1, acc01, 0, 0, 0);
        acc10 = __builtin_amdgcn_mfma_f32_16x16x32_bf16(a1, b0, acc10, 0, 0, 0);
        acc11 = __builtin_amdgcn_mfma_f32_16x16x32_bf16(a1, b1, acc11, 0, 0, 0);
    }

    const f32x4* accs[4] = { &acc00, &acc01, &acc10, &acc11 };
    #pragma unroll
    for (int i = 0; i < 2; ++i) {
        #pragma unroll
        for (int j = 0; j < 2; ++j) {
            const f32x4& a = *accs[i * 2 + j];
            #pragma unroll
            for (int r = 0; r < 4; ++r) {
                int m = m0 + wm * 32 + i * 16 + quad * 4 + r;
                int n = n0 + wn * 32 + j * 16 + l16;
                float v = a[r];
                if (mode == 0)
                    ept[(long long)zz * 262144 + (long long)m * 512 + n] =
                        f2b(__builtin_amdgcn_exp2f(C2 * v));
                else if (mode == 1)
                    hp[(long long)m * 512 + n] = C2 * (v + battn[n]);
                else
                    hh[(long long)m * 512 + n] = v;
            }
        }
    }
}

// =============== wave reductions ============================================
__device__ inline float wred_sum(float v) {
    #pragma unroll
    for (int i = 32; i > 0; i >>= 1) v += __shfl_xor(v, i);
    return v;
}
__device__ inline float wred_max(float v) {
    #pragma unroll
    for (int i = 32; i > 0; i >>= 1) v = fmaxf(v, __shfl_xor(v, i));
    return v;
}

// =============== energies + masked softmax + wc (fused, dual-t) ==============
// r4 structure + k-pair reciprocal fusion:
//   Wv_k/A + Wv_k1/B = (Wv_k*B + Wv_k1*A) * rcp(A*B)
// halves v_rcp count (trans pipe ~8cyc/wave vs 2 for fma) at +2 fma per pair.
// Exact algebra (same s-accumulator); A*B <= ~1e21 for this data, no overflow;
// a pathological inf denominator gives rcp=0 == the true ~0 contribution.
// 1024-thr occupancy is VGPR-gated at 1 block/CU (r10: LDS cut -> null), so
// instruction count, not residency, is the lever. pa restored to r4's
// single-pass 64KB layout (r10's two-pass cost +1.2us for nothing).
__device__ inline void proc8p(uint4 c0, uint4 c1, float4 hw0, float4 hw1,
                              float* a0, float* a1) {
    u32 p[4] = {c0.x, c0.y, c0.z, c0.w};
    u32 q[4] = {c1.x, c1.y, c1.z, c1.w};
    #pragma unroll
    for (int i = 0; i < 4; ++i) {
        float x0l = __uint_as_float(p[i] << 16);
        float x0h = __uint_as_float(p[i] & 0xFFFF0000u);
        float x1l = __uint_as_float(q[i] << 16);
        float x1h = __uint_as_float(q[i] & 0xFFFF0000u);
        float A, B, num;
        // t0, s = 2i
        A = fmaf(hw0.x, x0l, 1.f);
        B = fmaf(hw1.x, x1l, 1.f);
        num = fmaf(hw0.z, B, hw1.z * A);
        a0[2*i]   = fmaf(num, __builtin_amdgcn_rcpf(A * B), a0[2*i]);
        // t0, s = 2i+1
        A = fmaf(hw0.x, x0h, 1.f);
        B = fmaf(hw1.x, x1h, 1.f);
        num = fmaf(hw0.z, B, hw1.z * A);
        a0[2*i+1] = fmaf(num, __builtin_amdgcn_rcpf(A * B), a0[2*i+1]);
        // t1, s = 2i
        A = fmaf(hw0.y, x0l, 1.f);
        B = fmaf(hw1.y, x1l, 1.f);
        num = fmaf(hw0.z, B, hw1.z * A);
        a1[2*i]   = fmaf(num, __builtin_amdgcn_rcpf(A * B), a1[2*i]);
        // t1, s = 2i+1
        A = fmaf(hw0.y, x0h, 1.f);
        B = fmaf(hw1.y, x1h, 1.f);
        num = fmaf(hw0.z, B, hw1.z * A);
        a1[2*i+1] = fmaf(num, __builtin_amdgcn_rcpf(A * B), a1[2*i+1]);
    }
}
__device__ inline void wcproc2(uint4 c, float2 ap, float* acc0, float* acc1) {
    u32 cc[4] = {c.x, c.y, c.z, c.w};
    #pragma unroll
    for (int i = 0; i < 4; ++i) {
        float el = __uint_as_float(cc[i] << 16);
        float eh = __uint_as_float(cc[i] & 0xFFFF0000u);
        acc0[2*i]   = fmaf(ap.x, el, acc0[2*i]);
        acc0[2*i+1] = fmaf(ap.x, eh, acc0[2*i+1]);
        acc1[2*i]   = fmaf(ap.y, el, acc1[2*i]);
        acc1[2*i+1] = fmaf(ap.y, eh, acc1[2*i+1]);
    }
}

__global__ __launch_bounds__(1024) void energies(
    const float* __restrict__ maskp, const float* __restrict__ hp,
    const u16* __restrict__ ept, const float* __restrict__ Wv,
    const float* __restrict__ bvp, const u16* __restrict__ enc_bf,
    float* __restrict__ attn, float* __restrict__ wc)
{
    __shared__ __align__(16) float4 hpw[512];   // (e^{2hp_t0}, e^{2hp_t1}, Wv, -) 8KB
    __shared__ float pa[2][16][512];            // 64KB partials; reused for wc
    __shared__ float aL[512][2];                // 4KB attn weights for wc
    __shared__ float red[16];
    const int tid = threadIdx.x;
    const int b  = blockIdx.x & 7;              // XCD-grouped
    const int t0 = (blockIdx.x >> 3) * 2;
    const int th = tid >> 9;                    // 0: waves 0-7 (t0), 1: waves 8-15 (t0+1)
    const int k5 = tid & 511;
    const long long row0 = (long long)(b * 128 + t0) * 512;

    // ---- setup: hpw + sumWv ----
    float hv = hp[row0 + (long long)th * 512 + k5];
    float eh = __builtin_amdgcn_exp2f(hv);
    float* hpwf = (float*)hpw;
    hpwf[k5 * 4 + th] = eh;
    float w = 0.f;
    if (th == 0) { w = Wv[k5]; hpwf[k5 * 4 + 2] = w; }
    float wsum = wred_sum(w);
    if ((tid & 63) == 0) red[tid >> 6] = wsum;  // th==1 waves write 0: harmless
    __syncthreads();                            // hpw + red visible
    float sumWv = 0.f;
    #pragma unroll
    for (int i = 0; i < 16; ++i) sumWv += red[i];

    // ---- main loop: A[s] = sum_k Wv_k / (e^{2hp}*e^{2ep} + 1), both t ----
    const int kg = tid >> 6, sl = tid & 63;     // kg = wave: 32 k-rows; 8 s-cols
    const int s0 = sl * 8;
    const u16* eb = ept + (long long)b * 262144 + (kg * 32) * 512 + s0;
    const float4* hq = &hpw[kg * 32];

    float a0[8] = {0,0,0,0,0,0,0,0}, a1[8] = {0,0,0,0,0,0,0,0};
    uint4 c0 = *(const uint4*)(eb);
    uint4 c1 = *(const uint4*)(eb + 512);
    for (int kk = 0; kk < 30; kk += 2) {
        const u16* nb = eb + (kk + 2) * 512;
        uint4 n0 = *(const uint4*)(nb);
        uint4 n1 = *(const uint4*)(nb + 512);
        proc8p(c0, c1, hq[kk], hq[kk + 1], a0, a1);
        c0 = n0; c1 = n1;
    }
    proc8p(c0, c1, hq[30], hq[31], a0, a1);

    *(float4*)&pa[0][kg][s0]     = make_float4(a0[0], a0[1], a0[2], a0[3]);
    *(float4*)&pa[0][kg][s0 + 4] = make_float4(a0[4], a0[5], a0[6], a0[7]);
    *(float4*)&pa[1][kg][s0]     = make_float4(a1[0], a1[1], a1[2], a1[3]);
    *(float4*)&pa[1][kg][s0 + 4] = make_float4(a1[4], a1[5], a1[6], a1[7]);
    __syncthreads();

    // ---- softmax: thread owns (t = th, s = k5); each wave is one th ----
    float A = 0.f;
    #pragma unroll
    for (int g = 0; g < 16; ++g) A += pa[th][g][k5];   // stride-1 lanes
    float mv = maskp[(long long)b * 512 + k5];
    float bv0 = bvp[0];
    float r = (bv0 + sumWv - 2.f * A) * mv; r *= mv;

    float vmax = wred_max(r);
    if ((tid & 63) == 0) red[tid >> 6] = vmax;  // sumWv reads were pre-barrier
    __syncthreads();
    float mx = red[th * 8];
    #pragma unroll
    for (int i = 1; i < 8; ++i) mx = fmaxf(mx, red[th * 8 + i]);

    float ex = __builtin_amdgcn_exp2f((r - mx) * LOG2E) * mv;
    float vsum = wred_sum(ex);
    __syncthreads();                            // mx reads done before red reuse
    if ((tid & 63) == 0) red[tid >> 6] = vsum;
    __syncthreads();
    float sm = 0.f;
    #pragma unroll
    for (int i = 0; i < 8; ++i) sm += red[th * 8 + i];
    float at = ex * (1.f / (sm + 1e-6f));
    attn[row0 + (long long)th * 512 + k5] = at;
    aL[k5][th] = at;
    __syncthreads();                            // aL visible; pa free for reuse

    // ---- wc = attn @ enc: thread owns 8 e-cols (eg) x 32 s-rows (sg) ----
    const int eg = tid & 63, sg = tid >> 6;
    const u16* encb = enc_bf + (long long)b * 262144 + (long long)(sg * 32) * 512 + eg * 8;
    const float2* aq = (const float2*)&aL[sg * 32][0];
    float acc0[8] = {0,0,0,0,0,0,0,0}, acc1[8] = {0,0,0,0,0,0,0,0};
    uint4 e0 = *(const uint4*)(encb);
    uint4 e1 = *(const uint4*)(encb + 512);
    for (int j = 0; j < 30; j += 2) {
        uint4 f0 = *(const uint4*)(encb + (long long)(j + 2) * 512);
        uint4 f1 = *(const uint4*)(encb + (long long)(j + 3) * 512);
        wcproc2(e0, aq[j],     acc0, acc1);
        wcproc2(e1, aq[j + 1], acc0, acc1);
        e0 = f0; e1 = f1;
    }
    wcproc2(e0, aq[30], acc0, acc1);
    wcproc2(e1, aq[31], acc0, acc1);

    *(float4*)&pa[0][sg][eg * 8]     = make_float4(acc0[0], acc0[1], acc0[2], acc0[3]);
    *(float4*)&pa[0][sg][eg * 8 + 4] = make_float4(acc0[4], acc0[5], acc0[6], acc0[7]);
    *(float4*)&pa[1][sg][eg * 8]     = make_float4(acc1[0], acc1[1], acc1[2], acc1[3]);
    *(float4*)&pa[1][sg][eg * 8 + 4] = make_float4(acc1[4], acc1[5], acc1[6], acc1[7]);
    __syncthreads();

    float wcv = 0.f;
    #pragma unroll
    for (int g = 0; g < 16; ++g) wcv += pa[th][g][k5];
    wc[row0 + (long long)th * 512 + k5] = wcv;
}

// =============== hout: h_tilde = tanh(wc @ Wout[:,:512]^T + hh) ==============
__global__ __launch_bounds__(256) void hout_k(
    const float* __restrict__ wc, const u16* __restrict__ Wout_bf,
    float* __restrict__ out)
{
    __shared__ u16 lA[32 * LAS];
    __shared__ u16 lB[64 * LAS];
    const int tid = threadIdx.x;
    const int wvi = tid >> 6, ln = tid & 63;
    const int l16 = ln & 15, quad = ln >> 4;
    const int msub = wvi & 1, npair = wvi >> 1;
    const int m0 = blockIdx.y * 32, n0 = blockIdx.x * 64;
    const int rowA = tid >> 3, kofA = (tid & 7) * 4;
    const int rowB = tid >> 2, kofB = (tid & 3) * 8;
    f32x4 acc0 = {0,0,0,0}, acc1 = {0,0,0,0};

    for (int k0 = 0; k0 < 512; k0 += 32) {
        float4 av = *(const float4*)(wc + (long long)(m0 + rowA) * 512 + k0 + kofA);
        uint4 bv = *(const uint4*)(Wout_bf + (long long)(n0 + rowB) * 1024 + k0 + kofB);
        __syncthreads();
        *(uint2*)&lA[rowA * LAS + kofA] = make_uint2(pkcvt(av.x, av.y), pkcvt(av.z, av.w));
        int kk = kofB ^ (((rowB >> 3) & 3) << 3);
        *(uint4*)&lB[rowB * LAS + kk] = bv;
        __syncthreads();
        bf16x8 a = *(const bf16x8*)&lA[(msub * 16 + l16) * LAS + quad * 8];
        int nr0 = npair * 32 + l16, nr1 = nr0 + 16;
        bf16x8 b0 = *(const bf16x8*)&lB[nr0 * LAS + (quad * 8 ^ (((nr0 >> 3) & 3) << 3))];
        bf16x8 b1 = *(const bf16x8*)&lB[nr1 * LAS + (quad * 8 ^ (((nr1 >> 3) & 3) << 3))];
        acc0 = __builtin_amdgcn_mfma_f32_16x16x32_bf16(a, b0, acc0, 0, 0, 0);
        acc1 = __builtin_amdgcn_mfma_f32_16x16x32_bf16(a, b1, acc1, 0, 0, 0);
    }
    #pragma unroll
    for (int j = 0; j < 2; ++j) {
        const f32x4& a = j ? acc1 : acc0;
        #pragma unroll
        for (int r = 0; r < 4; ++r) {
            int m = m0 + msub * 16 + quad * 4 + r;
            int n = n0 + npair * 32 + j * 16 + l16;
            long long idx = (long long)m * 512 + n;
            out[idx] = tanh_fast(a[r] + out[idx]);   // out[idx] holds hh
        }
    }
}

extern "C" void kernel_launch(void* const* d_in, const int* in_sizes, int n_in,
                              void* d_out, int out_size, void* d_ws, size_t ws_size,
                              hipStream_t stream)
{
    const float* hidden = (const float*)d_in[0];  // (8,128,512)
    const float* enc    = (const float*)d_in[1];  // (8,512,512)
    const float* mask   = (const float*)d_in[2];  // (8,512)
    const float* Wattn  = (const float*)d_in[3];  // (512,1024)
    const float* battn  = (const float*)d_in[4];  // (512,)
    const float* Wv     = (const float*)d_in[5];  // (512,)
    const float* bvp    = (const float*)d_in[6];  // (1,)
    const float* Wout   = (const float*)d_in[7];  // (512,1024)
    float* out = (float*)d_out;

    float* hp  = (float*)d_ws;                      // @0   2MB fp32
    u16*   ept = (u16*)((char*)d_ws + (2 << 20));   // @2M  4MB bf16 (exp2 domain)
    u16*   bfp = (u16*)((char*)d_ws + (6 << 20));   // @6M  7MB bf16 pool
    u16* enc_bf    = bfp;                // 2M elems
    u16* hidden_bf = bfp + 2097152;      // 512K
    u16* Wattn_bf  = bfp + 2621440;      // 512K
    u16* Wout_bf   = bfp + 3145728;      // 512K

    tobf<<<1792, 256, 0, stream>>>(enc, hidden, Wattn, Wout, bfp);
    proj<<<768, 256, 0, stream>>>(hidden_bf, enc_bf, Wattn_bf, battn, Wout_bf,
                                  hp, ept, out /* hh in-place */);
    energies<<<512, 1024, 0, stream>>>(mask, hp, ept, Wv, bvp, enc_bf,
                                       out + OUT_ATTN, out + OUT_WC);
    hout_k<<<dim3(8, 32, 1), 256, 0, stream>>>(out + OUT_WC, Wout_bf, out);
}

// Round 12
// 137.664 us; speedup vs baseline: 3.6399x; 1.0175x over previous
//
#include <hip/hip_runtime.h>
#include <hip/hip_bf16.h>
#include <math.h>

typedef unsigned short u16;
typedef unsigned int u32;
typedef __bf16 bf16x8 __attribute__((ext_vector_type(8)));
typedef float f32x4 __attribute__((ext_vector_type(4)));

// B=8, T=128, S=512, E=D=512, fp32 in/out. d_out: h_tilde | wc | attn (fp32).
#define OUT_WC   524288LL
#define OUT_ATTN 1048576LL
#define C2 2.8853900817779268f   // 2*log2(e)
#define LOG2E 1.4426950408889634f
#define LAS 40                   // LDS row stride (u16): 32 + 8 pad

__device__ inline u16 f2b(float f) {
    return (u16)((__float_as_uint(f) + 0x8000u) >> 16);
}
__device__ inline u32 pkcvt(float x, float y) {
    __hip_bfloat162 h = __float22bfloat162_rn(make_float2(x, y));
    return *(u32*)&h;
}
__device__ inline float tanh_fast(float x) {
    return 1.f - 2.f * __builtin_amdgcn_rcpf(__builtin_amdgcn_exp2f(C2 * x) + 1.f);
}

// =============== tobf: fp32 -> bf16 pre-convert (enc|hidden|Wattn|Wout) ======
__global__ __launch_bounds__(256) void tobf(
    const float* __restrict__ enc, const float* __restrict__ hidden,
    const float* __restrict__ Wattn, const float* __restrict__ Wout,
    u16* __restrict__ dst)
{
    long long i = ((long long)blockIdx.x * 256 + threadIdx.x) * 8;
    const float* src; long long off;
    if (i < 2097152)      { src = enc;    off = i; }
    else if (i < 2621440) { src = hidden; off = i - 2097152; }
    else if (i < 3145728) { src = Wattn;  off = i - 2621440; }
    else                  { src = Wout;   off = i - 3145728; }
    float4 v0 = *(const float4*)(src + off);
    float4 v1 = *(const float4*)(src + off + 4);
    *(uint4*)(dst + i) = make_uint4(pkcvt(v0.x, v0.y), pkcvt(v0.z, v0.w),
                                    pkcvt(v1.x, v1.y), pkcvt(v1.z, v1.w));
}

// =============== proj: ept + hp + hh fused, 768 blocks, 64x64 tiles ==========
__global__ __launch_bounds__(256) void proj(
    const u16* __restrict__ hidden_bf, const u16* __restrict__ enc_bf,
    const u16* __restrict__ Wattn_bf, const float* __restrict__ battn,
    const u16* __restrict__ Wout_bf,
    float* __restrict__ hp, u16* __restrict__ ept, float* __restrict__ hh)
{
    __shared__ u16 lA[64 * LAS];
    __shared__ u16 lB[64 * LAS];
    const int tid = threadIdx.x;
    const int wvi = tid >> 6, ln = tid & 63;
    const int wm = wvi >> 1, wn = wvi & 1;
    const int l16 = ln & 15, quad = ln >> 4;
    const int blk = blockIdx.x;
    int bx, by, zz = 0, lda, ldb, mode;
    const u16 *A, *B;
    if (blk < 512) {
        mode = 0;
        zz = blk >> 6; by = (blk >> 3) & 7; bx = blk & 7;
        A = Wattn_bf + 512; lda = 1024;
        B = enc_bf + (long long)zz * 262144; ldb = 512;
    } else if (blk < 640) {
        mode = 1;
        int i = blk - 512; by = i >> 3; bx = i & 7;
        A = hidden_bf; lda = 512;
        B = Wattn_bf; ldb = 1024;
    } else {
        mode = 2;
        int i = blk - 640; by = i >> 3; bx = i & 7;
        A = hidden_bf; lda = 512;
        B = Wout_bf + 512; ldb = 1024;
    }
    const int m0 = by * 64, n0 = bx * 64;
    const int srow = tid >> 2, skof = (tid & 3) * 8;
    const u16* Ap = A + (long long)(m0 + srow) * lda + skof;
    const u16* Bp = B + (long long)(n0 + srow) * ldb + skof;

    f32x4 acc00 = {0,0,0,0}, acc01 = {0,0,0,0}, acc10 = {0,0,0,0}, acc11 = {0,0,0,0};

    for (int k0 = 0; k0 < 512; k0 += 32) {
        uint4 av = *(const uint4*)(Ap + k0);
        uint4 bv = *(const uint4*)(Bp + k0);
        __syncthreads();
        *(uint4*)&lA[srow * LAS + skof] = av;
        *(uint4*)&lB[srow * LAS + skof] = bv;
        __syncthreads();
        bf16x8 a0 = *(const bf16x8*)&lA[(wm * 32      + l16) * LAS + quad * 8];
        bf16x8 a1 = *(const bf16x8*)&lA[(wm * 32 + 16 + l16) * LAS + quad * 8];
        bf16x8 b0 = *(const bf16x8*)&lB[(wn * 32      + l16) * LAS + quad * 8];
        bf16x8 b1 = *(const bf16x8*)&lB[(wn * 32 + 16 + l16) * LAS + quad * 8];
        acc00 = __builtin_amdgcn_mfma_f32_16x16x32_bf16(a0, b0, acc00, 0, 0, 0);
        acc01 = __builtin_amdgcn_mfma_f32_16x16x32_bf16(a0, b1, acc01, 0, 0, 0);
        acc10 = __builtin_amdgcn_mfma_f32_16x16x32_bf16(a1, b0, acc10, 0, 0, 0);
        acc11 = __builtin_amdgcn_mfma_f32_16x16x32_bf16(a1, b1, acc11, 0, 0, 0);
    }

    const f32x4* accs[4] = { &acc00, &acc01, &acc10, &acc11 };
    #pragma unroll
    for (int i = 0; i < 2; ++i) {
        #pragma unroll
        for (int j = 0; j < 2; ++j) {
            const f32x4& a = *accs[i * 2 + j];
            #pragma unroll
            for (int r = 0; r < 4; ++r) {
                int m = m0 + wm * 32 + i * 16 + quad * 4 + r;
                int n = n0 + wn * 32 + j * 16 + l16;
                float v = a[r];
                if (mode == 0)
                    ept[(long long)zz * 262144 + (long long)m * 512 + n] =
                        f2b(__builtin_amdgcn_exp2f(C2 * v));
                else if (mode == 1)
                    hp[(long long)m * 512 + n] = C2 * (v + battn[n]);
                else
                    hh[(long long)m * 512 + n] = v;
            }
        }
    }
}

// =============== wave/block reductions ======================================
__device__ inline float wred_sum(float v) {
    #pragma unroll
    for (int i = 32; i > 0; i >>= 1) v += __shfl_xor(v, i);
    return v;
}
__device__ inline void bred2_max(float v0, float v1, float* red, int tid,
                                 float* o0, float* o1) {
    #pragma unroll
    for (int i = 32; i > 0; i >>= 1) {
        v0 = fmaxf(v0, __shfl_xor(v0, i));
        v1 = fmaxf(v1, __shfl_xor(v1, i));
    }
    __syncthreads();
    if ((tid & 63) == 0) { red[tid >> 6] = v0; red[8 + (tid >> 6)] = v1; }
    __syncthreads();
    float a0 = red[0], a1 = red[8];
    #pragma unroll
    for (int i = 1; i < 8; ++i) { a0 = fmaxf(a0, red[i]); a1 = fmaxf(a1, red[8 + i]); }
    *o0 = a0; *o1 = a1;
}
__device__ inline void bred2_sum(float v0, float v1, float* red, int tid,
                                 float* o0, float* o1) {
    #pragma unroll
    for (int i = 32; i > 0; i >>= 1) { v0 += __shfl_xor(v0, i); v1 += __shfl_xor(v1, i); }
    __syncthreads();
    if ((tid & 63) == 0) { red[tid >> 6] = v0; red[8 + (tid >> 6)] = v1; }
    __syncthreads();
    float a0 = 0.f, a1 = 0.f;
    #pragma unroll
    for (int i = 0; i < 8; ++i) { a0 += red[i]; a1 += red[8 + i]; }
    *o0 = a0; *o1 = a1;
}

// =============== energies + masked softmax + wc (fused, dual-t) ==============
// 512 blocks x 512 threads (8 waves). Same per-thread math as r11 (k-pair
// rcp fusion), but half-size blocks: the occupancy table across 7 variants
// shows 1024-thr blocks never get a 2nd block/CU at VGPR>32, while 512-thr
// blocks don't need all-4-SIMD placement. 2 blocks/CU co-resident -> 16
// waves/CU guaranteed. LDS cut to ~28.8KB via two-pass pa[8][512].
// b = bid & 7: XCD-grouped (ept[b]+enc_bf[b] ~1MB fits the 4MB XCD L2).
__device__ inline void proc8p(uint4 c0, uint4 c1, float4 hw0, float4 hw1,
                              float* a0, float* a1) {
    u32 p[4] = {c0.x, c0.y, c0.z, c0.w};
    u32 q[4] = {c1.x, c1.y, c1.z, c1.w};
    #pragma unroll
    for (int i = 0; i < 4; ++i) {
        float x0l = __uint_as_float(p[i] << 16);
        float x0h = __uint_as_float(p[i] & 0xFFFF0000u);
        float x1l = __uint_as_float(q[i] << 16);
        float x1h = __uint_as_float(q[i] & 0xFFFF0000u);
        float A, B, num;
        A = fmaf(hw0.x, x0l, 1.f);
        B = fmaf(hw1.x, x1l, 1.f);
        num = fmaf(hw0.z, B, hw1.z * A);
        a0[2*i]   = fmaf(num, __builtin_amdgcn_rcpf(A * B), a0[2*i]);
        A = fmaf(hw0.x, x0h, 1.f);
        B = fmaf(hw1.x, x1h, 1.f);
        num = fmaf(hw0.z, B, hw1.z * A);
        a0[2*i+1] = fmaf(num, __builtin_amdgcn_rcpf(A * B), a0[2*i+1]);
        A = fmaf(hw0.y, x0l, 1.f);
        B = fmaf(hw1.y, x1l, 1.f);
        num = fmaf(hw0.z, B, hw1.z * A);
        a1[2*i]   = fmaf(num, __builtin_amdgcn_rcpf(A * B), a1[2*i]);
        A = fmaf(hw0.y, x0h, 1.f);
        B = fmaf(hw1.y, x1h, 1.f);
        num = fmaf(hw0.z, B, hw1.z * A);
        a1[2*i+1] = fmaf(num, __builtin_amdgcn_rcpf(A * B), a1[2*i+1]);
    }
}
__device__ inline void wcproc2(uint4 c, float2 ap, float* acc0, float* acc1) {
    u32 cc[4] = {c.x, c.y, c.z, c.w};
    #pragma unroll
    for (int i = 0; i < 4; ++i) {
        float el = __uint_as_float(cc[i] << 16);
        float eh = __uint_as_float(cc[i] & 0xFFFF0000u);
        acc0[2*i]   = fmaf(ap.x, el, acc0[2*i]);
        acc0[2*i+1] = fmaf(ap.x, eh, acc0[2*i+1]);
        acc1[2*i]   = fmaf(ap.y, el, acc1[2*i]);
        acc1[2*i+1] = fmaf(ap.y, eh, acc1[2*i+1]);
    }
}

__global__ __launch_bounds__(512) void energies(
    const float* __restrict__ maskp, const float* __restrict__ hp,
    const u16* __restrict__ ept, const float* __restrict__ Wv,
    const float* __restrict__ bvp, const u16* __restrict__ enc_bf,
    float* __restrict__ attn, float* __restrict__ wc)
{
    __shared__ __align__(16) float4 hpw[512];   // (e^{2hp_t0}, e^{2hp_t1}, Wv, -) 8KB
    __shared__ float pa[8][512];                // 16KB partials, two passes; wc reuse
    __shared__ float aL[512][2];                // 4KB attn weights for wc
    __shared__ float red[16];
    const int tid = threadIdx.x;
    const int b  = blockIdx.x & 7;              // XCD-grouped
    const int t0 = (blockIdx.x >> 3) * 2;
    const long long row0 = (long long)(b * 128 + t0) * 512;

    // ---- setup: hpw (both t rows) + sumWv ----
    float hv0 = hp[row0 + tid];
    float hv1 = hp[row0 + 512 + tid];
    float w = Wv[tid];
    hpw[tid] = make_float4(__builtin_amdgcn_exp2f(hv0),
                           __builtin_amdgcn_exp2f(hv1), w, 0.f);
    float wsum = wred_sum(w);
    if ((tid & 63) == 0) red[tid >> 6] = wsum;
    __syncthreads();                            // hpw + red visible
    float sumWv = 0.f;
    #pragma unroll
    for (int i = 0; i < 8; ++i) sumWv += red[i];

    // ---- main loop: wave kg owns 64 k-rows; thread: 8 s-cols, both t ----
    const int kg = tid >> 6, sl = tid & 63;
    const int s0 = sl * 8;
    const u16* eb = ept + (long long)b * 262144 + (kg * 64) * 512 + s0;
    const float4* hq = &hpw[kg * 64];

    float a0[8] = {0,0,0,0,0,0,0,0}, a1[8] = {0,0,0,0,0,0,0,0};
    uint4 c0 = *(const uint4*)(eb);
    uint4 c1 = *(const uint4*)(eb + 512);
    for (int kk = 0; kk < 62; kk += 2) {
        const u16* nb = eb + (kk + 2) * 512;
        uint4 n0 = *(const uint4*)(nb);
        uint4 n1 = *(const uint4*)(nb + 512);
        proc8p(c0, c1, hq[kk], hq[kk + 1], a0, a1);
        c0 = n0; c1 = n1;
    }
    proc8p(c0, c1, hq[62], hq[63], a0, a1);

    // ---- two-pass cross-wave reduction through 16KB pa ----
    *(float4*)&pa[kg][s0]     = make_float4(a0[0], a0[1], a0[2], a0[3]);
    *(float4*)&pa[kg][s0 + 4] = make_float4(a0[4], a0[5], a0[6], a0[7]);
    __syncthreads();
    float A0 = 0.f, A1 = 0.f;
    #pragma unroll
    for (int g = 0; g < 8; ++g) A0 += pa[g][tid];      // stride-1 lanes
    __syncthreads();                            // reads done before overwrite
    *(float4*)&pa[kg][s0]     = make_float4(a1[0], a1[1], a1[2], a1[3]);
    *(float4*)&pa[kg][s0 + 4] = make_float4(a1[4], a1[5], a1[6], a1[7]);
    __syncthreads();
    #pragma unroll
    for (int g = 0; g < 8; ++g) A1 += pa[g][tid];

    // ---- softmax: thread owns s = tid, both t-rows ----
    const int s = tid;
    float mv = maskp[(long long)b * 512 + s];
    float bv0 = bvp[0];
    float r0 = (bv0 + sumWv - 2.f * A0) * mv; r0 *= mv;
    float r1 = (bv0 + sumWv - 2.f * A1) * mv; r1 *= mv;

    float mx0, mx1;
    bred2_max(r0, r1, red, tid, &mx0, &mx1);
    float ex0 = __builtin_amdgcn_exp2f((r0 - mx0) * LOG2E) * mv;
    float ex1 = __builtin_amdgcn_exp2f((r1 - mx1) * LOG2E) * mv;
    float sm0, sm1;
    bred2_sum(ex0, ex1, red, tid, &sm0, &sm1);
    float at0 = ex0 * (1.f / (sm0 + 1e-6f));
    float at1 = ex1 * (1.f / (sm1 + 1e-6f));
    attn[row0 + s]       = at0;
    attn[row0 + 512 + s] = at1;
    aL[s][0] = at0; aL[s][1] = at1;
    __syncthreads();                            // aL visible; pa free for reuse

    // ---- wc = attn @ enc: thread owns 8 e-cols (eg) x 64 s-rows (sg) ----
    const int eg = tid & 63, sg = tid >> 6;
    const u16* encb = enc_bf + (long long)b * 262144 + (long long)(sg * 64) * 512 + eg * 8;
    const float2* aq = (const float2*)&aL[sg * 64][0];
    float acc0[8] = {0,0,0,0,0,0,0,0}, acc1[8] = {0,0,0,0,0,0,0,0};
    uint4 e0 = *(const uint4*)(encb);
    uint4 e1 = *(const uint4*)(encb + 512);
    for (int j = 0; j < 62; j += 2) {
        uint4 f0 = *(const uint4*)(encb + (long long)(j + 2) * 512);
        uint4 f1 = *(const uint4*)(encb + (long long)(j + 3) * 512);
        wcproc2(e0, aq[j],     acc0, acc1);
        wcproc2(e1, aq[j + 1], acc0, acc1);
        e0 = f0; e1 = f1;
    }
    wcproc2(e0, aq[62], acc0, acc1);
    wcproc2(e1, aq[63], acc0, acc1);

    // ---- two-pass wc reduction through pa ----
    *(float4*)&pa[sg][eg * 8]     = make_float4(acc0[0], acc0[1], acc0[2], acc0[3]);
    *(float4*)&pa[sg][eg * 8 + 4] = make_float4(acc0[4], acc0[5], acc0[6], acc0[7]);
    __syncthreads();
    float wcv0 = 0.f, wcv1 = 0.f;
    #pragma unroll
    for (int g = 0; g < 8; ++g) wcv0 += pa[g][tid];
    __syncthreads();                            // reads done before overwrite
    *(float4*)&pa[sg][eg * 8]     = make_float4(acc1[0], acc1[1], acc1[2], acc1[3]);
    *(float4*)&pa[sg][eg * 8 + 4] = make_float4(acc1[4], acc1[5], acc1[6], acc1[7]);
    __syncthreads();
    #pragma unroll
    for (int g = 0; g < 8; ++g) wcv1 += pa[g][tid];
    wc[row0 + tid]       = wcv0;
    wc[row0 + 512 + tid] = wcv1;
}

// =============== hout: h_tilde = tanh(wc @ Wout[:,:512]^T + hh) ==============
__global__ __launch_bounds__(256) void hout_k(
    const float* __restrict__ wc, const u16* __restrict__ Wout_bf,
    float* __restrict__ out)
{
    __shared__ u16 lA[32 * LAS];
    __shared__ u16 lB[64 * LAS];
    const int tid = threadIdx.x;
    const int wvi = tid >> 6, ln = tid & 63;
    const int l16 = ln & 15, quad = ln >> 4;
    const int msub = wvi & 1, npair = wvi >> 1;
    const int m0 = blockIdx.y * 32, n0 = blockIdx.x * 64;
    const int rowA = tid >> 3, kofA = (tid & 7) * 4;
    const int rowB = tid >> 2, kofB = (tid & 3) * 8;
    f32x4 acc0 = {0,0,0,0}, acc1 = {0,0,0,0};

    for (int k0 = 0; k0 < 512; k0 += 32) {
        float4 av = *(const float4*)(wc + (long long)(m0 + rowA) * 512 + k0 + kofA);
        uint4 bv = *(const uint4*)(Wout_bf + (long long)(n0 + rowB) * 1024 + k0 + kofB);
        __syncthreads();
        *(uint2*)&lA[rowA * LAS + kofA] = make_uint2(pkcvt(av.x, av.y), pkcvt(av.z, av.w));
        int kk = kofB ^ (((rowB >> 3) & 3) << 3);
        *(uint4*)&lB[rowB * LAS + kk] = bv;
        __syncthreads();
        bf16x8 a = *(const bf16x8*)&lA[(msub * 16 + l16) * LAS + quad * 8];
        int nr0 = npair * 32 + l16, nr1 = nr0 + 16;
        bf16x8 b0 = *(const bf16x8*)&lB[nr0 * LAS + (quad * 8 ^ (((nr0 >> 3) & 3) << 3))];
        bf16x8 b1 = *(const bf16x8*)&lB[nr1 * LAS + (quad * 8 ^ (((nr1 >> 3) & 3) << 3))];
        acc0 = __builtin_amdgcn_mfma_f32_16x16x32_bf16(a, b0, acc0, 0, 0, 0);
        acc1 = __builtin_amdgcn_mfma_f32_16x16x32_bf16(a, b1, acc1, 0, 0, 0);
    }
    #pragma unroll
    for (int j = 0; j < 2; ++j) {
        const f32x4& a = j ? acc1 : acc0;
        #pragma unroll
        for (int r = 0; r < 4; ++r) {
            int m = m0 + msub * 16 + quad * 4 + r;
            int n = n0 + npair * 32 + j * 16 + l16;
            long long idx = (long long)m * 512 + n;
            out[idx] = tanh_fast(a[r] + out[idx]);   // out[idx] holds hh
        }
    }
}

extern "C" void kernel_launch(void* const* d_in, const int* in_sizes, int n_in,
                              void* d_out, int out_size, void* d_ws, size_t ws_size,
                              hipStream_t stream)
{
    const float* hidden = (const float*)d_in[0];  // (8,128,512)
    const float* enc    = (const float*)d_in[1];  // (8,512,512)
    const float* mask   = (const float*)d_in[2];  // (8,512)
    const float* Wattn  = (const float*)d_in[3];  // (512,1024)
    const float* battn  = (const float*)d_in[4];  // (512,)
    const float* Wv     = (const float*)d_in[5];  // (512,)
    const float* bvp    = (const float*)d_in[6];  // (1,)
    const float* Wout   = (const float*)d_in[7];  // (512,1024)
    float* out = (float*)d_out;

    float* hp  = (float*)d_ws;                      // @0   2MB fp32
    u16*   ept = (u16*)((char*)d_ws + (2 << 20));   // @2M  4MB bf16 (exp2 domain)
    u16*   bfp = (u16*)((char*)d_ws + (6 << 20));   // @6M  7MB bf16 pool
    u16* enc_bf    = bfp;                // 2M elems
    u16* hidden_bf = bfp + 2097152;      // 512K
    u16* Wattn_bf  = bfp + 2621440;      // 512K
    u16* Wout_bf   = bfp + 3145728;      // 512K

    tobf<<<1792, 256, 0, stream>>>(enc, hidden, Wattn, Wout, bfp);
    proj<<<768, 256, 0, stream>>>(hidden_bf, enc_bf, Wattn_bf, battn, Wout_bf,
                                  hp, ept, out /* hh in-place */);
    energies<<<512, 512, 0, stream>>>(mask, hp, ept, Wv, bvp, enc_bf,
                                      out + OUT_ATTN, out + OUT_WC);
    hout_k<<<dim3(8, 32, 1), 256, 0, stream>>>(out + OUT_WC, Wout_bf, out);
}

// Round 13
// 137.040 us; speedup vs baseline: 3.6564x; 1.0046x over previous
//
#include <hip/hip_runtime.h>
#include <hip/hip_bf16.h>
#include <math.h>

typedef unsigned short u16;
typedef unsigned int u32;
typedef __bf16 bf16x8 __attribute__((ext_vector_type(8)));
typedef float f32x4 __attribute__((ext_vector_type(4)));

// B=8, T=128, S=512, E=D=512, fp32 in/out. d_out: h_tilde | wc | attn (fp32).
#define OUT_WC   524288LL
#define OUT_ATTN 1048576LL
#define C2 2.8853900817779268f   // 2*log2(e)
#define LOG2E 1.4426950408889634f
#define LAS 40                   // LDS row stride (u16) BK=32: 32 + 8
#define LAS2 72                  // LDS row stride (u16) BK=64: 64 + 8

__device__ inline u16 f2b(float f) {
    return (u16)((__float_as_uint(f) + 0x8000u) >> 16);
}
__device__ inline u32 pkcvt(float x, float y) {
    __hip_bfloat162 h = __float22bfloat162_rn(make_float2(x, y));
    return *(u32*)&h;
}
__device__ inline float tanh_fast(float x) {
    return 1.f - 2.f * __builtin_amdgcn_rcpf(__builtin_amdgcn_exp2f(C2 * x) + 1.f);
}

// =============== tobf: fp32 -> bf16 pre-convert (enc|hidden|Wattn|Wout) ======
__global__ __launch_bounds__(256) void tobf(
    const float* __restrict__ enc, const float* __restrict__ hidden,
    const float* __restrict__ Wattn, const float* __restrict__ Wout,
    u16* __restrict__ dst)
{
    long long i = ((long long)blockIdx.x * 256 + threadIdx.x) * 8;
    const float* src; long long off;
    if (i < 2097152)      { src = enc;    off = i; }
    else if (i < 2621440) { src = hidden; off = i - 2097152; }
    else if (i < 3145728) { src = Wattn;  off = i - 2621440; }
    else                  { src = Wout;   off = i - 3145728; }
    float4 v0 = *(const float4*)(src + off);
    float4 v1 = *(const float4*)(src + off + 4);
    *(uint4*)(dst + i) = make_uint4(pkcvt(v0.x, v0.y), pkcvt(v0.z, v0.w),
                                    pkcvt(v1.x, v1.y), pkcvt(v1.z, v1.w));
}

// =============== proj: ept + hp + hh fused, 768 blocks, 64x64 tiles ==========
// BK=64 register-prefetch pipeline on bf16 inputs: 8 iterations (half the
// barriers of the BK=32 loop), next k-slab loads issued between barrier-2 and
// the MFMA section so L2 latency hides under compute (r6's test of this was
// confounded by simultaneous fp32-input absorption; bf16 inputs kept here).
__global__ __launch_bounds__(256) void proj(
    const u16* __restrict__ hidden_bf, const u16* __restrict__ enc_bf,
    const u16* __restrict__ Wattn_bf, const float* __restrict__ battn,
    const u16* __restrict__ Wout_bf,
    float* __restrict__ hp, u16* __restrict__ ept, float* __restrict__ hh)
{
    __shared__ u16 lA[64 * LAS2];   // 9216 u16 = 18.4KB
    __shared__ u16 lB[64 * LAS2];
    const int tid = threadIdx.x;
    const int wvi = tid >> 6, ln = tid & 63;
    const int wm = wvi >> 1, wn = wvi & 1;
    const int l16 = ln & 15, quad = ln >> 4;
    const int blk = blockIdx.x;
    int bx, by, zz = 0, lda, ldb, mode;
    const u16 *A, *B;
    if (blk < 512) {
        mode = 0;
        zz = blk >> 6; by = (blk >> 3) & 7; bx = blk & 7;
        A = Wattn_bf + 512; lda = 1024;
        B = enc_bf + (long long)zz * 262144; ldb = 512;
    } else if (blk < 640) {
        mode = 1;
        int i = blk - 512; by = i >> 3; bx = i & 7;
        A = hidden_bf; lda = 512;
        B = Wattn_bf; ldb = 1024;
    } else {
        mode = 2;
        int i = blk - 640; by = i >> 3; bx = i & 7;
        A = hidden_bf; lda = 512;
        B = Wout_bf + 512; ldb = 1024;
    }
    const int m0 = by * 64, n0 = bx * 64;
    const int srow = tid >> 2, skof = (tid & 3) * 16;   // 4 thr/row, 16 u16 each
    const u16* Ap = A + (long long)(m0 + srow) * lda + skof;
    const u16* Bp = B + (long long)(n0 + srow) * ldb + skof;

    f32x4 acc00 = {0,0,0,0}, acc01 = {0,0,0,0}, acc10 = {0,0,0,0}, acc11 = {0,0,0,0};

    uint4 qa0, qa1, qb0, qb1;
    #define PROJ_LOADK(k0) do { \
        qa0 = *(const uint4*)(Ap + (k0));     qa1 = *(const uint4*)(Ap + (k0) + 8); \
        qb0 = *(const uint4*)(Bp + (k0));     qb1 = *(const uint4*)(Bp + (k0) + 8); } while (0)

    PROJ_LOADK(0);
    for (int step = 0; step < 8; ++step) {
        __syncthreads();
        *(uint4*)&lA[srow * LAS2 + skof]     = qa0;
        *(uint4*)&lA[srow * LAS2 + skof + 8] = qa1;
        *(uint4*)&lB[srow * LAS2 + skof]     = qb0;
        *(uint4*)&lB[srow * LAS2 + skof + 8] = qb1;
        __syncthreads();
        if (step < 7) PROJ_LOADK((step + 1) * 64);   // overlaps MFMA below
        #pragma unroll
        for (int kh = 0; kh < 2; ++kh) {
            bf16x8 a0 = *(const bf16x8*)&lA[(wm * 32      + l16) * LAS2 + kh * 32 + quad * 8];
            bf16x8 a1 = *(const bf16x8*)&lA[(wm * 32 + 16 + l16) * LAS2 + kh * 32 + quad * 8];
            bf16x8 b0 = *(const bf16x8*)&lB[(wn * 32      + l16) * LAS2 + kh * 32 + quad * 8];
            bf16x8 b1 = *(const bf16x8*)&lB[(wn * 32 + 16 + l16) * LAS2 + kh * 32 + quad * 8];
            acc00 = __builtin_amdgcn_mfma_f32_16x16x32_bf16(a0, b0, acc00, 0, 0, 0);
            acc01 = __builtin_amdgcn_mfma_f32_16x16x32_bf16(a0, b1, acc01, 0, 0, 0);
            acc10 = __builtin_amdgcn_mfma_f32_16x16x32_bf16(a1, b0, acc10, 0, 0, 0);
            acc11 = __builtin_amdgcn_mfma_f32_16x16x32_bf16(a1, b1, acc11, 0, 0, 0);
        }
    }
    #undef PROJ_LOADK

    const f32x4* accs[4] = { &acc00, &acc01, &acc10, &acc11 };
    #pragma unroll
    for (int i = 0; i < 2; ++i) {
        #pragma unroll
        for (int j = 0; j < 2; ++j) {
            const f32x4& a = *accs[i * 2 + j];
            #pragma unroll
            for (int r = 0; r < 4; ++r) {
                int m = m0 + wm * 32 + i * 16 + quad * 4 + r;
                int n = n0 + wn * 32 + j * 16 + l16;
                float v = a[r];
                if (mode == 0)
                    ept[(long long)zz * 262144 + (long long)m * 512 + n] =
                        f2b(__builtin_amdgcn_exp2f(C2 * v));
                else if (mode == 1)
                    hp[(long long)m * 512 + n] = C2 * (v + battn[n]);
                else
                    hh[(long long)m * 512 + n] = v;
            }
        }
    }
}

// =============== wave/block reductions ======================================
__device__ inline float wred_sum(float v) {
    #pragma unroll
    for (int i = 32; i > 0; i >>= 1) v += __shfl_xor(v, i);
    return v;
}
__device__ inline void bred2_max(float v0, float v1, float* red, int tid,
                                 float* o0, float* o1) {
    #pragma unroll
    for (int i = 32; i > 0; i >>= 1) {
        v0 = fmaxf(v0, __shfl_xor(v0, i));
        v1 = fmaxf(v1, __shfl_xor(v1, i));
    }
    __syncthreads();
    if ((tid & 63) == 0) { red[tid >> 6] = v0; red[8 + (tid >> 6)] = v1; }
    __syncthreads();
    float a0 = red[0], a1 = red[8];
    #pragma unroll
    for (int i = 1; i < 8; ++i) { a0 = fmaxf(a0, red[i]); a1 = fmaxf(a1, red[8 + i]); }
    *o0 = a0; *o1 = a1;
}
__device__ inline void bred2_sum(float v0, float v1, float* red, int tid,
                                 float* o0, float* o1) {
    #pragma unroll
    for (int i = 32; i > 0; i >>= 1) { v0 += __shfl_xor(v0, i); v1 += __shfl_xor(v1, i); }
    __syncthreads();
    if ((tid & 63) == 0) { red[tid >> 6] = v0; red[8 + (tid >> 6)] = v1; }
    __syncthreads();
    float a0 = 0.f, a1 = 0.f;
    #pragma unroll
    for (int i = 0; i < 8; ++i) { a0 += red[i]; a1 += red[8 + i]; }
    *o0 = a0; *o1 = a1;
}

// =============== energies + masked softmax + wc (fused, dual-t) ==============
// 512 blocks x 512 threads (8 waves), k-pair rcp fusion. Single-pass
// pa[2][8][512] (32KB; r12's two-pass halved LDS but LDS was proven
// non-binding in r10 -- the extra barriers were pure cost). LDS total 45.1KB.
// b = bid & 7: XCD-grouped (ept[b]+enc_bf[b] ~1MB fits the 4MB XCD L2).
__device__ inline void proc8p(uint4 c0, uint4 c1, float4 hw0, float4 hw1,
                              float* a0, float* a1) {
    u32 p[4] = {c0.x, c0.y, c0.z, c0.w};
    u32 q[4] = {c1.x, c1.y, c1.z, c1.w};
    #pragma unroll
    for (int i = 0; i < 4; ++i) {
        float x0l = __uint_as_float(p[i] << 16);
        float x0h = __uint_as_float(p[i] & 0xFFFF0000u);
        float x1l = __uint_as_float(q[i] << 16);
        float x1h = __uint_as_float(q[i] & 0xFFFF0000u);
        float A, B, num;
        A = fmaf(hw0.x, x0l, 1.f);
        B = fmaf(hw1.x, x1l, 1.f);
        num = fmaf(hw0.z, B, hw1.z * A);
        a0[2*i]   = fmaf(num, __builtin_amdgcn_rcpf(A * B), a0[2*i]);
        A = fmaf(hw0.x, x0h, 1.f);
        B = fmaf(hw1.x, x1h, 1.f);
        num = fmaf(hw0.z, B, hw1.z * A);
        a0[2*i+1] = fmaf(num, __builtin_amdgcn_rcpf(A * B), a0[2*i+1]);
        A = fmaf(hw0.y, x0l, 1.f);
        B = fmaf(hw1.y, x1l, 1.f);
        num = fmaf(hw0.z, B, hw1.z * A);
        a1[2*i]   = fmaf(num, __builtin_amdgcn_rcpf(A * B), a1[2*i]);
        A = fmaf(hw0.y, x0h, 1.f);
        B = fmaf(hw1.y, x1h, 1.f);
        num = fmaf(hw0.z, B, hw1.z * A);
        a1[2*i+1] = fmaf(num, __builtin_amdgcn_rcpf(A * B), a1[2*i+1]);
    }
}
__device__ inline void wcproc2(uint4 c, float2 ap, float* acc0, float* acc1) {
    u32 cc[4] = {c.x, c.y, c.z, c.w};
    #pragma unroll
    for (int i = 0; i < 4; ++i) {
        float el = __uint_as_float(cc[i] << 16);
        float eh = __uint_as_float(cc[i] & 0xFFFF0000u);
        acc0[2*i]   = fmaf(ap.x, el, acc0[2*i]);
        acc0[2*i+1] = fmaf(ap.x, eh, acc0[2*i+1]);
        acc1[2*i]   = fmaf(ap.y, el, acc1[2*i]);
        acc1[2*i+1] = fmaf(ap.y, eh, acc1[2*i+1]);
    }
}

__global__ __launch_bounds__(512) void energies(
    const float* __restrict__ maskp, const float* __restrict__ hp,
    const u16* __restrict__ ept, const float* __restrict__ Wv,
    const float* __restrict__ bvp, const u16* __restrict__ enc_bf,
    float* __restrict__ attn, float* __restrict__ wc)
{
    __shared__ __align__(16) float4 hpw[512];   // (e^{2hp_t0}, e^{2hp_t1}, Wv, -) 8KB
    __shared__ float pa[2][8][512];             // 32KB partials, single pass; wc reuse
    __shared__ float aL[512][2];                // 4KB attn weights for wc
    __shared__ float red[16];
    const int tid = threadIdx.x;
    const int b  = blockIdx.x & 7;              // XCD-grouped
    const int t0 = (blockIdx.x >> 3) * 2;
    const long long row0 = (long long)(b * 128 + t0) * 512;

    // ---- setup: hpw (both t rows) + sumWv ----
    float hv0 = hp[row0 + tid];
    float hv1 = hp[row0 + 512 + tid];
    float w = Wv[tid];
    hpw[tid] = make_float4(__builtin_amdgcn_exp2f(hv0),
                           __builtin_amdgcn_exp2f(hv1), w, 0.f);
    float wsum = wred_sum(w);
    if ((tid & 63) == 0) red[tid >> 6] = wsum;
    __syncthreads();                            // hpw + red visible
    float sumWv = 0.f;
    #pragma unroll
    for (int i = 0; i < 8; ++i) sumWv += red[i];

    // ---- main loop: wave kg owns 64 k-rows; thread: 8 s-cols, both t ----
    const int kg = tid >> 6, sl = tid & 63;
    const int s0 = sl * 8;
    const u16* eb = ept + (long long)b * 262144 + (kg * 64) * 512 + s0;
    const float4* hq = &hpw[kg * 64];

    float a0[8] = {0,0,0,0,0,0,0,0}, a1[8] = {0,0,0,0,0,0,0,0};
    uint4 c0 = *(const uint4*)(eb);
    uint4 c1 = *(const uint4*)(eb + 512);
    for (int kk = 0; kk < 62; kk += 2) {
        const u16* nb = eb + (kk + 2) * 512;
        uint4 n0 = *(const uint4*)(nb);
        uint4 n1 = *(const uint4*)(nb + 512);
        proc8p(c0, c1, hq[kk], hq[kk + 1], a0, a1);
        c0 = n0; c1 = n1;
    }
    proc8p(c0, c1, hq[62], hq[63], a0, a1);

    // ---- single-pass cross-wave reduction through 32KB pa ----
    *(float4*)&pa[0][kg][s0]     = make_float4(a0[0], a0[1], a0[2], a0[3]);
    *(float4*)&pa[0][kg][s0 + 4] = make_float4(a0[4], a0[5], a0[6], a0[7]);
    *(float4*)&pa[1][kg][s0]     = make_float4(a1[0], a1[1], a1[2], a1[3]);
    *(float4*)&pa[1][kg][s0 + 4] = make_float4(a1[4], a1[5], a1[6], a1[7]);
    __syncthreads();
    float A0 = 0.f, A1 = 0.f;
    #pragma unroll
    for (int g = 0; g < 8; ++g) { A0 += pa[0][g][tid]; A1 += pa[1][g][tid]; }

    // ---- softmax: thread owns s = tid, both t-rows ----
    const int s = tid;
    float mv = maskp[(long long)b * 512 + s];
    float bv0 = bvp[0];
    float r0 = (bv0 + sumWv - 2.f * A0) * mv; r0 *= mv;
    float r1 = (bv0 + sumWv - 2.f * A1) * mv; r1 *= mv;

    float mx0, mx1;
    bred2_max(r0, r1, red, tid, &mx0, &mx1);
    float ex0 = __builtin_amdgcn_exp2f((r0 - mx0) * LOG2E) * mv;
    float ex1 = __builtin_amdgcn_exp2f((r1 - mx1) * LOG2E) * mv;
    float sm0, sm1;
    bred2_sum(ex0, ex1, red, tid, &sm0, &sm1);
    float at0 = ex0 * (1.f / (sm0 + 1e-6f));
    float at1 = ex1 * (1.f / (sm1 + 1e-6f));
    attn[row0 + s]       = at0;
    attn[row0 + 512 + s] = at1;
    aL[s][0] = at0; aL[s][1] = at1;
    __syncthreads();                            // aL visible; pa free for reuse

    // ---- wc = attn @ enc: thread owns 8 e-cols (eg) x 64 s-rows (sg) ----
    const int eg = tid & 63, sg = tid >> 6;
    const u16* encb = enc_bf + (long long)b * 262144 + (long long)(sg * 64) * 512 + eg * 8;
    const float2* aq = (const float2*)&aL[sg * 64][0];
    float acc0[8] = {0,0,0,0,0,0,0,0}, acc1[8] = {0,0,0,0,0,0,0,0};
    uint4 e0 = *(const uint4*)(encb);
    uint4 e1 = *(const uint4*)(encb + 512);
    for (int j = 0; j < 62; j += 2) {
        uint4 f0 = *(const uint4*)(encb + (long long)(j + 2) * 512);
        uint4 f1 = *(const uint4*)(encb + (long long)(j + 3) * 512);
        wcproc2(e0, aq[j],     acc0, acc1);
        wcproc2(e1, aq[j + 1], acc0, acc1);
        e0 = f0; e1 = f1;
    }
    wcproc2(e0, aq[62], acc0, acc1);
    wcproc2(e1, aq[63], acc0, acc1);

    // ---- single-pass wc reduction through pa ----
    *(float4*)&pa[0][sg][eg * 8]     = make_float4(acc0[0], acc0[1], acc0[2], acc0[3]);
    *(float4*)&pa[0][sg][eg * 8 + 4] = make_float4(acc0[4], acc0[5], acc0[6], acc0[7]);
    *(float4*)&pa[1][sg][eg * 8]     = make_float4(acc1[0], acc1[1], acc1[2], acc1[3]);
    *(float4*)&pa[1][sg][eg * 8 + 4] = make_float4(acc1[4], acc1[5], acc1[6], acc1[7]);
    __syncthreads();
    float wcv0 = 0.f, wcv1 = 0.f;
    #pragma unroll
    for (int g = 0; g < 8; ++g) { wcv0 += pa[0][g][tid]; wcv1 += pa[1][g][tid]; }
    wc[row0 + tid]       = wcv0;
    wc[row0 + 512 + tid] = wcv1;
}

// =============== hout: h_tilde = tanh(wc @ Wout[:,:512]^T + hh) ==============
__global__ __launch_bounds__(256) void hout_k(
    const float* __restrict__ wc, const u16* __restrict__ Wout_bf,
    float* __restrict__ out)
{
    __shared__ u16 lA[32 * LAS];
    __shared__ u16 lB[64 * LAS];
    const int tid = threadIdx.x;
    const int wvi = tid >> 6, ln = tid & 63;
    const int l16 = ln & 15, quad = ln >> 4;
    const int msub = wvi & 1, npair = wvi >> 1;
    const int m0 = blockIdx.y * 32, n0 = blockIdx.x * 64;
    const int rowA = tid >> 3, kofA = (tid & 7) * 4;
    const int rowB = tid >> 2, kofB = (tid & 3) * 8;
    f32x4 acc0 = {0,0,0,0}, acc1 = {0,0,0,0};

    for (int k0 = 0; k0 < 512; k0 += 32) {
        float4 av = *(const float4*)(wc + (long long)(m0 + rowA) * 512 + k0 + kofA);
        uint4 bv = *(const uint4*)(Wout_bf + (long long)(n0 + rowB) * 1024 + k0 + kofB);
        __syncthreads();
        *(uint2*)&lA[rowA * LAS + kofA] = make_uint2(pkcvt(av.x, av.y), pkcvt(av.z, av.w));
        int kk = kofB ^ (((rowB >> 3) & 3) << 3);
        *(uint4*)&lB[rowB * LAS + kk] = bv;
        __syncthreads();
        bf16x8 a = *(const bf16x8*)&lA[(msub * 16 + l16) * LAS + quad * 8];
        int nr0 = npair * 32 + l16, nr1 = nr0 + 16;
        bf16x8 b0 = *(const bf16x8*)&lB[nr0 * LAS + (quad * 8 ^ (((nr0 >> 3) & 3) << 3))];
        bf16x8 b1 = *(const bf16x8*)&lB[nr1 * LAS + (quad * 8 ^ (((nr1 >> 3) & 3) << 3))];
        acc0 = __builtin_amdgcn_mfma_f32_16x16x32_bf16(a, b0, acc0, 0, 0, 0);
        acc1 = __builtin_amdgcn_mfma_f32_16x16x32_bf16(a, b1, acc1, 0, 0, 0);
    }
    #pragma unroll
    for (int j = 0; j < 2; ++j) {
        const f32x4& a = j ? acc1 : acc0;
        #pragma unroll
        for (int r = 0; r < 4; ++r) {
            int m = m0 + msub * 16 + quad * 4 + r;
            int n = n0 + npair * 32 + j * 16 + l16;
            long long idx = (long long)m * 512 + n;
            out[idx] = tanh_fast(a[r] + out[idx]);   // out[idx] holds hh
        }
    }
}

extern "C" void kernel_launch(void* const* d_in, const int* in_sizes, int n_in,
                              void* d_out, int out_size, void* d_ws, size_t ws_size,
                              hipStream_t stream)
{
    const float* hidden = (const float*)d_in[0];  // (8,128,512)
    const float* enc    = (const float*)d_in[1];  // (8,512,512)
    const float* mask   = (const float*)d_in[2];  // (8,512)
    const float* Wattn  = (const float*)d_in[3];  // (512,1024)
    const float* battn  = (const float*)d_in[4];  // (512,)
    const float* Wv     = (const float*)d_in[5];  // (512,)
    const float* bvp    = (const float*)d_in[6];  // (1,)
    const float* Wout   = (const float*)d_in[7];  // (512,1024)
    float* out = (float*)d_out;

    float* hp  = (float*)d_ws;                      // @0   2MB fp32
    u16*   ept = (u16*)((char*)d_ws + (2 << 20));   // @2M  4MB bf16 (exp2 domain)
    u16*   bfp = (u16*)((char*)d_ws + (6 << 20));   // @6M  7MB bf16 pool
    u16* enc_bf    = bfp;                // 2M elems
    u16* hidden_bf = bfp + 2097152;      // 512K
    u16* Wattn_bf  = bfp + 2621440;      // 512K
    u16* Wout_bf   = bfp + 3145728;      // 512K

    tobf<<<1792, 256, 0, stream>>>(enc, hidden, Wattn, Wout, bfp);
    proj<<<768, 256, 0, stream>>>(hidden_bf, enc_bf, Wattn_bf, battn, Wout_bf,
                                  hp, ept, out /* hh in-place */);
    energies<<<512, 512, 0, stream>>>(mask, hp, ept, Wv, bvp, enc_bf,
                                      out + OUT_ATTN, out + OUT_WC);
    hout_k<<<dim3(8, 32, 1), 256, 0, stream>>>(out + OUT_WC, Wout_bf, out);
}

// Round 14
// 136.773 us; speedup vs baseline: 3.6636x; 1.0020x over previous
//
#include <hip/hip_runtime.h>
#include <hip/hip_bf16.h>
#include <math.h>

typedef unsigned short u16;
typedef unsigned int u32;
typedef __bf16 bf16x8 __attribute__((ext_vector_type(8)));
typedef float f32x4 __attribute__((ext_vector_type(4)));

// B=8, T=128, S=512, E=D=512, fp32 in/out. d_out: h_tilde | wc | attn (fp32).
#define OUT_WC   524288LL
#define OUT_ATTN 1048576LL
#define C2 2.8853900817779268f   // 2*log2(e)
#define LOG2E 1.4426950408889634f
#define LAS 40                   // LDS row stride (u16) BK=32: 32 + 8
#define LAS2 72                  // LDS row stride (u16) BK=64: 64 + 8

__device__ inline u16 f2b(float f) {
    return (u16)((__float_as_uint(f) + 0x8000u) >> 16);
}
__device__ inline u32 pkcvt(float x, float y) {
    __hip_bfloat162 h = __float22bfloat162_rn(make_float2(x, y));
    return *(u32*)&h;
}
__device__ inline float tanh_fast(float x) {
    return 1.f - 2.f * __builtin_amdgcn_rcpf(__builtin_amdgcn_exp2f(C2 * x) + 1.f);
}

// =============== tobf: fp32 -> bf16 pre-convert (enc|hidden|Wattn|Wout) ======
__global__ __launch_bounds__(256) void tobf(
    const float* __restrict__ enc, const float* __restrict__ hidden,
    const float* __restrict__ Wattn, const float* __restrict__ Wout,
    u16* __restrict__ dst)
{
    long long i = ((long long)blockIdx.x * 256 + threadIdx.x) * 8;
    const float* src; long long off;
    if (i < 2097152)      { src = enc;    off = i; }
    else if (i < 2621440) { src = hidden; off = i - 2097152; }
    else if (i < 3145728) { src = Wattn;  off = i - 2621440; }
    else                  { src = Wout;   off = i - 3145728; }
    float4 v0 = *(const float4*)(src + off);
    float4 v1 = *(const float4*)(src + off + 4);
    *(uint4*)(dst + i) = make_uint4(pkcvt(v0.x, v0.y), pkcvt(v0.z, v0.w),
                                    pkcvt(v1.x, v1.y), pkcvt(v1.z, v1.w));
}

// =============== proj: ept + hp + hh fused, 768 blocks, 64x64 tiles ==========
// BK=64, TWO-DEEP register prefetch (q/r slab sets): each slab's global loads
// are issued a full k-step (~300+ cyc of MFMA+barriers) before the vmcnt-wait
// at its LDS write, instead of r13's ~80 cyc. Discriminating experiment:
// if proj is latency-bound (~29us), this halves it; if proj is already small,
// total is unchanged and the residual is launch overhead.
__global__ __launch_bounds__(256) void proj(
    const u16* __restrict__ hidden_bf, const u16* __restrict__ enc_bf,
    const u16* __restrict__ Wattn_bf, const float* __restrict__ battn,
    const u16* __restrict__ Wout_bf,
    float* __restrict__ hp, u16* __restrict__ ept, float* __restrict__ hh)
{
    __shared__ u16 lA[64 * LAS2];   // 9216 u16 = 18.4KB total with lB
    __shared__ u16 lB[64 * LAS2];
    const int tid = threadIdx.x;
    const int wvi = tid >> 6, ln = tid & 63;
    const int wm = wvi >> 1, wn = wvi & 1;
    const int l16 = ln & 15, quad = ln >> 4;
    const int blk = blockIdx.x;
    int bx, by, zz = 0, lda, ldb, mode;
    const u16 *A, *B;
    if (blk < 512) {
        mode = 0;
        zz = blk >> 6; by = (blk >> 3) & 7; bx = blk & 7;
        A = Wattn_bf + 512; lda = 1024;
        B = enc_bf + (long long)zz * 262144; ldb = 512;
    } else if (blk < 640) {
        mode = 1;
        int i = blk - 512; by = i >> 3; bx = i & 7;
        A = hidden_bf; lda = 512;
        B = Wattn_bf; ldb = 1024;
    } else {
        mode = 2;
        int i = blk - 640; by = i >> 3; bx = i & 7;
        A = hidden_bf; lda = 512;
        B = Wout_bf + 512; ldb = 1024;
    }
    const int m0 = by * 64, n0 = bx * 64;
    const int srow = tid >> 2, skof = (tid & 3) * 16;   // 4 thr/row, 16 u16 each
    const u16* Ap = A + (long long)(m0 + srow) * lda + skof;
    const u16* Bp = B + (long long)(n0 + srow) * ldb + skof;

    f32x4 acc00 = {0,0,0,0}, acc01 = {0,0,0,0}, acc10 = {0,0,0,0}, acc11 = {0,0,0,0};

    uint4 qa0, qa1, qb0, qb1;   // even-step slab
    uint4 ra0, ra1, rb0, rb1;   // odd-step slab
    #define LOADQ(k0) do { \
        qa0 = *(const uint4*)(Ap + (k0));     qa1 = *(const uint4*)(Ap + (k0) + 8); \
        qb0 = *(const uint4*)(Bp + (k0));     qb1 = *(const uint4*)(Bp + (k0) + 8); } while (0)
    #define LOADR(k0) do { \
        ra0 = *(const uint4*)(Ap + (k0));     ra1 = *(const uint4*)(Ap + (k0) + 8); \
        rb0 = *(const uint4*)(Bp + (k0));     rb1 = *(const uint4*)(Bp + (k0) + 8); } while (0)
    #define MFMA_STEP() do { \
        _Pragma("unroll") \
        for (int kh = 0; kh < 2; ++kh) { \
            bf16x8 a0 = *(const bf16x8*)&lA[(wm * 32      + l16) * LAS2 + kh * 32 + quad * 8]; \
            bf16x8 a1 = *(const bf16x8*)&lA[(wm * 32 + 16 + l16) * LAS2 + kh * 32 + quad * 8]; \
            bf16x8 b0 = *(const bf16x8*)&lB[(wn * 32      + l16) * LAS2 + kh * 32 + quad * 8]; \
            bf16x8 b1 = *(const bf16x8*)&lB[(wn * 32 + 16 + l16) * LAS2 + kh * 32 + quad * 8]; \
            acc00 = __builtin_amdgcn_mfma_f32_16x16x32_bf16(a0, b0, acc00, 0, 0, 0); \
            acc01 = __builtin_amdgcn_mfma_f32_16x16x32_bf16(a0, b1, acc01, 0, 0, 0); \
            acc10 = __builtin_amdgcn_mfma_f32_16x16x32_bf16(a1, b0, acc10, 0, 0, 0); \
            acc11 = __builtin_amdgcn_mfma_f32_16x16x32_bf16(a1, b1, acc11, 0, 0, 0); \
        } } while (0)

    LOADQ(0);
    LOADR(64);
    #pragma unroll
    for (int it = 0; it < 4; ++it) {
        // even step (slab q), k = it*128
        __syncthreads();
        *(uint4*)&lA[srow * LAS2 + skof]     = qa0;
        *(uint4*)&lA[srow * LAS2 + skof + 8] = qa1;
        *(uint4*)&lB[srow * LAS2 + skof]     = qb0;
        *(uint4*)&lB[srow * LAS2 + skof + 8] = qb1;
        __syncthreads();
        if (it < 3) LOADQ(it * 128 + 128);   // 2 steps ahead
        MFMA_STEP();
        // odd step (slab r), k = it*128 + 64
        __syncthreads();
        *(uint4*)&lA[srow * LAS2 + skof]     = ra0;
        *(uint4*)&lA[srow * LAS2 + skof + 8] = ra1;
        *(uint4*)&lB[srow * LAS2 + skof]     = rb0;
        *(uint4*)&lB[srow * LAS2 + skof + 8] = rb1;
        __syncthreads();
        if (it < 3) LOADR(it * 128 + 192);   // 2 steps ahead
        MFMA_STEP();
    }
    #undef LOADQ
    #undef LOADR
    #undef MFMA_STEP

    const f32x4* accs[4] = { &acc00, &acc01, &acc10, &acc11 };
    #pragma unroll
    for (int i = 0; i < 2; ++i) {
        #pragma unroll
        for (int j = 0; j < 2; ++j) {
            const f32x4& a = *accs[i * 2 + j];
            #pragma unroll
            for (int r = 0; r < 4; ++r) {
                int m = m0 + wm * 32 + i * 16 + quad * 4 + r;
                int n = n0 + wn * 32 + j * 16 + l16;
                float v = a[r];
                if (mode == 0)
                    ept[(long long)zz * 262144 + (long long)m * 512 + n] =
                        f2b(__builtin_amdgcn_exp2f(C2 * v));
                else if (mode == 1)
                    hp[(long long)m * 512 + n] = C2 * (v + battn[n]);
                else
                    hh[(long long)m * 512 + n] = v;
            }
        }
    }
}

// =============== wave/block reductions ======================================
__device__ inline float wred_sum(float v) {
    #pragma unroll
    for (int i = 32; i > 0; i >>= 1) v += __shfl_xor(v, i);
    return v;
}
__device__ inline void bred2_max(float v0, float v1, float* red, int tid,
                                 float* o0, float* o1) {
    #pragma unroll
    for (int i = 32; i > 0; i >>= 1) {
        v0 = fmaxf(v0, __shfl_xor(v0, i));
        v1 = fmaxf(v1, __shfl_xor(v1, i));
    }
    __syncthreads();
    if ((tid & 63) == 0) { red[tid >> 6] = v0; red[8 + (tid >> 6)] = v1; }
    __syncthreads();
    float a0 = red[0], a1 = red[8];
    #pragma unroll
    for (int i = 1; i < 8; ++i) { a0 = fmaxf(a0, red[i]); a1 = fmaxf(a1, red[8 + i]); }
    *o0 = a0; *o1 = a1;
}
__device__ inline void bred2_sum(float v0, float v1, float* red, int tid,
                                 float* o0, float* o1) {
    #pragma unroll
    for (int i = 32; i > 0; i >>= 1) { v0 += __shfl_xor(v0, i); v1 += __shfl_xor(v1, i); }
    __syncthreads();
    if ((tid & 63) == 0) { red[tid >> 6] = v0; red[8 + (tid >> 6)] = v1; }
    __syncthreads();
    float a0 = 0.f, a1 = 0.f;
    #pragma unroll
    for (int i = 0; i < 8; ++i) { a0 += red[i]; a1 += red[8 + i]; }
    *o0 = a0; *o1 = a1;
}

// =============== energies + masked softmax + wc (fused, dual-t) ==============
// r13 verbatim: 512 blocks x 512 threads (8 waves), k-pair rcp fusion,
// single-pass pa[2][8][512]. Near its issue-bound floor (VALUBusy ~62%).
__device__ inline void proc8p(uint4 c0, uint4 c1, float4 hw0, float4 hw1,
                              float* a0, float* a1) {
    u32 p[4] = {c0.x, c0.y, c0.z, c0.w};
    u32 q[4] = {c1.x, c1.y, c1.z, c1.w};
    #pragma unroll
    for (int i = 0; i < 4; ++i) {
        float x0l = __uint_as_float(p[i] << 16);
        float x0h = __uint_as_float(p[i] & 0xFFFF0000u);
        float x1l = __uint_as_float(q[i] << 16);
        float x1h = __uint_as_float(q[i] & 0xFFFF0000u);
        float A, B, num;
        A = fmaf(hw0.x, x0l, 1.f);
        B = fmaf(hw1.x, x1l, 1.f);
        num = fmaf(hw0.z, B, hw1.z * A);
        a0[2*i]   = fmaf(num, __builtin_amdgcn_rcpf(A * B), a0[2*i]);
        A = fmaf(hw0.x, x0h, 1.f);
        B = fmaf(hw1.x, x1h, 1.f);
        num = fmaf(hw0.z, B, hw1.z * A);
        a0[2*i+1] = fmaf(num, __builtin_amdgcn_rcpf(A * B), a0[2*i+1]);
        A = fmaf(hw0.y, x0l, 1.f);
        B = fmaf(hw1.y, x1l, 1.f);
        num = fmaf(hw0.z, B, hw1.z * A);
        a1[2*i]   = fmaf(num, __builtin_amdgcn_rcpf(A * B), a1[2*i]);
        A = fmaf(hw0.y, x0h, 1.f);
        B = fmaf(hw1.y, x1h, 1.f);
        num = fmaf(hw0.z, B, hw1.z * A);
        a1[2*i+1] = fmaf(num, __builtin_amdgcn_rcpf(A * B), a1[2*i+1]);
    }
}
__device__ inline void wcproc2(uint4 c, float2 ap, float* acc0, float* acc1) {
    u32 cc[4] = {c.x, c.y, c.z, c.w};
    #pragma unroll
    for (int i = 0; i < 4; ++i) {
        float el = __uint_as_float(cc[i] << 16);
        float eh = __uint_as_float(cc[i] & 0xFFFF0000u);
        acc0[2*i]   = fmaf(ap.x, el, acc0[2*i]);
        acc0[2*i+1] = fmaf(ap.x, eh, acc0[2*i+1]);
        acc1[2*i]   = fmaf(ap.y, el, acc1[2*i]);
        acc1[2*i+1] = fmaf(ap.y, eh, acc1[2*i+1]);
    }
}

__global__ __launch_bounds__(512) void energies(
    const float* __restrict__ maskp, const float* __restrict__ hp,
    const u16* __restrict__ ept, const float* __restrict__ Wv,
    const float* __restrict__ bvp, const u16* __restrict__ enc_bf,
    float* __restrict__ attn, float* __restrict__ wc)
{
    __shared__ __align__(16) float4 hpw[512];   // (e^{2hp_t0}, e^{2hp_t1}, Wv, -) 8KB
    __shared__ float pa[2][8][512];             // 32KB partials, single pass; wc reuse
    __shared__ float aL[512][2];                // 4KB attn weights for wc
    __shared__ float red[16];
    const int tid = threadIdx.x;
    const int b  = blockIdx.x & 7;              // XCD-grouped
    const int t0 = (blockIdx.x >> 3) * 2;
    const long long row0 = (long long)(b * 128 + t0) * 512;

    // ---- setup: hpw (both t rows) + sumWv ----
    float hv0 = hp[row0 + tid];
    float hv1 = hp[row0 + 512 + tid];
    float w = Wv[tid];
    hpw[tid] = make_float4(__builtin_amdgcn_exp2f(hv0),
                           __builtin_amdgcn_exp2f(hv1), w, 0.f);
    float wsum = wred_sum(w);
    if ((tid & 63) == 0) red[tid >> 6] = wsum;
    __syncthreads();                            // hpw + red visible
    float sumWv = 0.f;
    #pragma unroll
    for (int i = 0; i < 8; ++i) sumWv += red[i];

    // ---- main loop: wave kg owns 64 k-rows; thread: 8 s-cols, both t ----
    const int kg = tid >> 6, sl = tid & 63;
    const int s0 = sl * 8;
    const u16* eb = ept + (long long)b * 262144 + (kg * 64) * 512 + s0;
    const float4* hq = &hpw[kg * 64];

    float a0[8] = {0,0,0,0,0,0,0,0}, a1[8] = {0,0,0,0,0,0,0,0};
    uint4 c0 = *(const uint4*)(eb);
    uint4 c1 = *(const uint4*)(eb + 512);
    for (int kk = 0; kk < 62; kk += 2) {
        const u16* nb = eb + (kk + 2) * 512;
        uint4 n0 = *(const uint4*)(nb);
        uint4 n1 = *(const uint4*)(nb + 512);
        proc8p(c0, c1, hq[kk], hq[kk + 1], a0, a1);
        c0 = n0; c1 = n1;
    }
    proc8p(c0, c1, hq[62], hq[63], a0, a1);

    // ---- single-pass cross-wave reduction through 32KB pa ----
    *(float4*)&pa[0][kg][s0]     = make_float4(a0[0], a0[1], a0[2], a0[3]);
    *(float4*)&pa[0][kg][s0 + 4] = make_float4(a0[4], a0[5], a0[6], a0[7]);
    *(float4*)&pa[1][kg][s0]     = make_float4(a1[0], a1[1], a1[2], a1[3]);
    *(float4*)&pa[1][kg][s0 + 4] = make_float4(a1[4], a1[5], a1[6], a1[7]);
    __syncthreads();
    float A0 = 0.f, A1 = 0.f;
    #pragma unroll
    for (int g = 0; g < 8; ++g) { A0 += pa[0][g][tid]; A1 += pa[1][g][tid]; }

    // ---- softmax: thread owns s = tid, both t-rows ----
    const int s = tid;
    float mv = maskp[(long long)b * 512 + s];
    float bv0 = bvp[0];
    float r0 = (bv0 + sumWv - 2.f * A0) * mv; r0 *= mv;
    float r1 = (bv0 + sumWv - 2.f * A1) * mv; r1 *= mv;

    float mx0, mx1;
    bred2_max(r0, r1, red, tid, &mx0, &mx1);
    float ex0 = __builtin_amdgcn_exp2f((r0 - mx0) * LOG2E) * mv;
    float ex1 = __builtin_amdgcn_exp2f((r1 - mx1) * LOG2E) * mv;
    float sm0, sm1;
    bred2_sum(ex0, ex1, red, tid, &sm0, &sm1);
    float at0 = ex0 * (1.f / (sm0 + 1e-6f));
    float at1 = ex1 * (1.f / (sm1 + 1e-6f));
    attn[row0 + s]       = at0;
    attn[row0 + 512 + s] = at1;
    aL[s][0] = at0; aL[s][1] = at1;
    __syncthreads();                            // aL visible; pa free for reuse

    // ---- wc = attn @ enc: thread owns 8 e-cols (eg) x 64 s-rows (sg) ----
    const int eg = tid & 63, sg = tid >> 6;
    const u16* encb = enc_bf + (long long)b * 262144 + (long long)(sg * 64) * 512 + eg * 8;
    const float2* aq = (const float2*)&aL[sg * 64][0];
    float acc0[8] = {0,0,0,0,0,0,0,0}, acc1[8] = {0,0,0,0,0,0,0,0};
    uint4 e0 = *(const uint4*)(encb);
    uint4 e1 = *(const uint4*)(encb + 512);
    for (int j = 0; j < 62; j += 2) {
        uint4 f0 = *(const uint4*)(encb + (long long)(j + 2) * 512);
        uint4 f1 = *(const uint4*)(encb + (long long)(j + 3) * 512);
        wcproc2(e0, aq[j],     acc0, acc1);
        wcproc2(e1, aq[j + 1], acc0, acc1);
        e0 = f0; e1 = f1;
    }
    wcproc2(e0, aq[62], acc0, acc1);
    wcproc2(e1, aq[63], acc0, acc1);

    // ---- single-pass wc reduction through pa ----
    *(float4*)&pa[0][sg][eg * 8]     = make_float4(acc0[0], acc0[1], acc0[2], acc0[3]);
    *(float4*)&pa[0][sg][eg * 8 + 4] = make_float4(acc0[4], acc0[5], acc0[6], acc0[7]);
    *(float4*)&pa[1][sg][eg * 8]     = make_float4(acc1[0], acc1[1], acc1[2], acc1[3]);
    *(float4*)&pa[1][sg][eg * 8 + 4] = make_float4(acc1[4], acc1[5], acc1[6], acc1[7]);
    __syncthreads();
    float wcv0 = 0.f, wcv1 = 0.f;
    #pragma unroll
    for (int g = 0; g < 8; ++g) { wcv0 += pa[0][g][tid]; wcv1 += pa[1][g][tid]; }
    wc[row0 + tid]       = wcv0;
    wc[row0 + 512 + tid] = wcv1;
}

// =============== hout: h_tilde = tanh(wc @ Wout[:,:512]^T + hh) ==============
__global__ __launch_bounds__(256) void hout_k(
    const float* __restrict__ wc, const u16* __restrict__ Wout_bf,
    float* __restrict__ out)
{
    __shared__ u16 lA[32 * LAS];
    __shared__ u16 lB[64 * LAS];
    const int tid = threadIdx.x;
    const int wvi = tid >> 6, ln = tid & 63;
    const int l16 = ln & 15, quad = ln >> 4;
    const int msub = wvi & 1, npair = wvi >> 1;
    const int m0 = blockIdx.y * 32, n0 = blockIdx.x * 64;
    const int rowA = tid >> 3, kofA = (tid & 7) * 4;
    const int rowB = tid >> 2, kofB = (tid & 3) * 8;
    f32x4 acc0 = {0,0,0,0}, acc1 = {0,0,0,0};

    for (int k0 = 0; k0 < 512; k0 += 32) {
        float4 av = *(const float4*)(wc + (long long)(m0 + rowA) * 512 + k0 + kofA);
        uint4 bv = *(const uint4*)(Wout_bf + (long long)(n0 + rowB) * 1024 + k0 + kofB);
        __syncthreads();
        *(uint2*)&lA[rowA * LAS + kofA] = make_uint2(pkcvt(av.x, av.y), pkcvt(av.z, av.w));
        int kk = kofB ^ (((rowB >> 3) & 3) << 3);
        *(uint4*)&lB[rowB * LAS + kk] = bv;
        __syncthreads();
        bf16x8 a = *(const bf16x8*)&lA[(msub * 16 + l16) * LAS + quad * 8];
        int nr0 = npair * 32 + l16, nr1 = nr0 + 16;
        bf16x8 b0 = *(const bf16x8*)&lB[nr0 * LAS + (quad * 8 ^ (((nr0 >> 3) & 3) << 3))];
        bf16x8 b1 = *(const bf16x8*)&lB[nr1 * LAS + (quad * 8 ^ (((nr1 >> 3) & 3) << 3))];
        acc0 = __builtin_amdgcn_mfma_f32_16x16x32_bf16(a, b0, acc0, 0, 0, 0);
        acc1 = __builtin_amdgcn_mfma_f32_16x16x32_bf16(a, b1, acc1, 0, 0, 0);
    }
    #pragma unroll
    for (int j = 0; j < 2; ++j) {
        const f32x4& a = j ? acc1 : acc0;
        #pragma unroll
        for (int r = 0; r < 4; ++r) {
            int m = m0 + msub * 16 + quad * 4 + r;
            int n = n0 + npair * 32 + j * 16 + l16;
            long long idx = (long long)m * 512 + n;
            out[idx] = tanh_fast(a[r] + out[idx]);   // out[idx] holds hh
        }
    }
}

extern "C" void kernel_launch(void* const* d_in, const int* in_sizes, int n_in,
                              void* d_out, int out_size, void* d_ws, size_t ws_size,
                              hipStream_t stream)
{
    const float* hidden = (const float*)d_in[0];  // (8,128,512)
    const float* enc    = (const float*)d_in[1];  // (8,512,512)
    const float* mask   = (const float*)d_in[2];  // (8,512)
    const float* Wattn  = (const float*)d_in[3];  // (512,1024)
    const float* battn  = (const float*)d_in[4];  // (512,)
    const float* Wv     = (const float*)d_in[5];  // (512,)
    const float* bvp    = (const float*)d_in[6];  // (1,)
    const float* Wout   = (const float*)d_in[7];  // (512,1024)
    float* out = (float*)d_out;

    float* hp  = (float*)d_ws;                      // @0   2MB fp32
    u16*   ept = (u16*)((char*)d_ws + (2 << 20));   // @2M  4MB bf16 (exp2 domain)
    u16*   bfp = (u16*)((char*)d_ws + (6 << 20));   // @6M  7MB bf16 pool
    u16* enc_bf    = bfp;                // 2M elems
    u16* hidden_bf = bfp + 2097152;      // 512K
    u16* Wattn_bf  = bfp + 2621440;      // 512K
    u16* Wout_bf   = bfp + 3145728;      // 512K

    tobf<<<1792, 256, 0, stream>>>(enc, hidden, Wattn, Wout, bfp);
    proj<<<768, 256, 0, stream>>>(hidden_bf, enc_bf, Wattn_bf, battn, Wout_bf,
                                  hp, ept, out /* hh in-place */);
    energies<<<512, 512, 0, stream>>>(mask, hp, ept, Wv, bvp, enc_bf,
                                      out + OUT_ATTN, out + OUT_WC);
    hout_k<<<dim3(8, 32, 1), 256, 0, stream>>>(out + OUT_WC, Wout_bf, out);
}

// Round 15
// 135.660 us; speedup vs baseline: 3.6936x; 1.0082x over previous
//
#include <hip/hip_runtime.h>
#include <hip/hip_bf16.h>
#include <math.h>

typedef unsigned short u16;
typedef unsigned int u32;
typedef __bf16 bf16x8 __attribute__((ext_vector_type(8)));
typedef float f32x4 __attribute__((ext_vector_type(4)));

// B=8, T=128, S=512, E=D=512, fp32 in/out. d_out: h_tilde | wc | attn (fp32).
#define OUT_WC   524288LL
#define OUT_ATTN 1048576LL
#define C2 2.8853900817779268f   // 2*log2(e)
#define LOG2E 1.4426950408889634f
#define LAS 40                   // LDS row stride (u16) BK=32: 32 + 8
#define LAS2 72                  // LDS row stride (u16) BK=64: 64 + 8

__device__ inline u16 f2b(float f) {
    return (u16)((__float_as_uint(f) + 0x8000u) >> 16);
}
__device__ inline u32 pkcvt(float x, float y) {
    __hip_bfloat162 h = __float22bfloat162_rn(make_float2(x, y));
    return *(u32*)&h;
}
__device__ inline float tanh_fast(float x) {
    return 1.f - 2.f * __builtin_amdgcn_rcpf(__builtin_amdgcn_exp2f(C2 * x) + 1.f);
}

// =============== tobf: fp32 -> bf16 pre-convert (enc|hidden|Wattn|Wout) ======
__global__ __launch_bounds__(256) void tobf(
    const float* __restrict__ enc, const float* __restrict__ hidden,
    const float* __restrict__ Wattn, const float* __restrict__ Wout,
    u16* __restrict__ dst)
{
    long long i = ((long long)blockIdx.x * 256 + threadIdx.x) * 8;
    const float* src; long long off;
    if (i < 2097152)      { src = enc;    off = i; }
    else if (i < 2621440) { src = hidden; off = i - 2097152; }
    else if (i < 3145728) { src = Wattn;  off = i - 2621440; }
    else                  { src = Wout;   off = i - 3145728; }
    float4 v0 = *(const float4*)(src + off);
    float4 v1 = *(const float4*)(src + off + 4);
    *(uint4*)(dst + i) = make_uint4(pkcvt(v0.x, v0.y), pkcvt(v0.z, v0.w),
                                    pkcvt(v1.x, v1.y), pkcvt(v1.z, v1.w));
}

// =============== proj: ept + hp + hh fused, 768 blocks, 64x64 tiles ==========
// BK=64, 2-deep register prefetch (r14; proj is small -- kept as-is).
__global__ __launch_bounds__(256) void proj(
    const u16* __restrict__ hidden_bf, const u16* __restrict__ enc_bf,
    const u16* __restrict__ Wattn_bf, const float* __restrict__ battn,
    const u16* __restrict__ Wout_bf,
    float* __restrict__ hp, u16* __restrict__ ept, float* __restrict__ hh)
{
    __shared__ u16 lA[64 * LAS2];
    __shared__ u16 lB[64 * LAS2];
    const int tid = threadIdx.x;
    const int wvi = tid >> 6, ln = tid & 63;
    const int wm = wvi >> 1, wn = wvi & 1;
    const int l16 = ln & 15, quad = ln >> 4;
    const int blk = blockIdx.x;
    int bx, by, zz = 0, lda, ldb, mode;
    const u16 *A, *B;
    if (blk < 512) {
        mode = 0;
        zz = blk >> 6; by = (blk >> 3) & 7; bx = blk & 7;
        A = Wattn_bf + 512; lda = 1024;
        B = enc_bf + (long long)zz * 262144; ldb = 512;
    } else if (blk < 640) {
        mode = 1;
        int i = blk - 512; by = i >> 3; bx = i & 7;
        A = hidden_bf; lda = 512;
        B = Wattn_bf; ldb = 1024;
    } else {
        mode = 2;
        int i = blk - 640; by = i >> 3; bx = i & 7;
        A = hidden_bf; lda = 512;
        B = Wout_bf + 512; ldb = 1024;
    }
    const int m0 = by * 64, n0 = bx * 64;
    const int srow = tid >> 2, skof = (tid & 3) * 16;
    const u16* Ap = A + (long long)(m0 + srow) * lda + skof;
    const u16* Bp = B + (long long)(n0 + srow) * ldb + skof;

    f32x4 acc00 = {0,0,0,0}, acc01 = {0,0,0,0}, acc10 = {0,0,0,0}, acc11 = {0,0,0,0};

    uint4 qa0, qa1, qb0, qb1;
    uint4 ra0, ra1, rb0, rb1;
    #define LOADQ(k0) do { \
        qa0 = *(const uint4*)(Ap + (k0));     qa1 = *(const uint4*)(Ap + (k0) + 8); \
        qb0 = *(const uint4*)(Bp + (k0));     qb1 = *(const uint4*)(Bp + (k0) + 8); } while (0)
    #define LOADR(k0) do { \
        ra0 = *(const uint4*)(Ap + (k0));     ra1 = *(const uint4*)(Ap + (k0) + 8); \
        rb0 = *(const uint4*)(Bp + (k0));     rb1 = *(const uint4*)(Bp + (k0) + 8); } while (0)
    #define MFMA_STEP() do { \
        _Pragma("unroll") \
        for (int kh = 0; kh < 2; ++kh) { \
            bf16x8 a0 = *(const bf16x8*)&lA[(wm * 32      + l16) * LAS2 + kh * 32 + quad * 8]; \
            bf16x8 a1 = *(const bf16x8*)&lA[(wm * 32 + 16 + l16) * LAS2 + kh * 32 + quad * 8]; \
            bf16x8 b0 = *(const bf16x8*)&lB[(wn * 32      + l16) * LAS2 + kh * 32 + quad * 8]; \
            bf16x8 b1 = *(const bf16x8*)&lB[(wn * 32 + 16 + l16) * LAS2 + kh * 32 + quad * 8]; \
            acc00 = __builtin_amdgcn_mfma_f32_16x16x32_bf16(a0, b0, acc00, 0, 0, 0); \
            acc01 = __builtin_amdgcn_mfma_f32_16x16x32_bf16(a0, b1, acc01, 0, 0, 0); \
            acc10 = __builtin_amdgcn_mfma_f32_16x16x32_bf16(a1, b0, acc10, 0, 0, 0); \
            acc11 = __builtin_amdgcn_mfma_f32_16x16x32_bf16(a1, b1, acc11, 0, 0, 0); \
        } } while (0)

    LOADQ(0);
    LOADR(64);
    #pragma unroll
    for (int it = 0; it < 4; ++it) {
        __syncthreads();
        *(uint4*)&lA[srow * LAS2 + skof]     = qa0;
        *(uint4*)&lA[srow * LAS2 + skof + 8] = qa1;
        *(uint4*)&lB[srow * LAS2 + skof]     = qb0;
        *(uint4*)&lB[srow * LAS2 + skof + 8] = qb1;
        __syncthreads();
        if (it < 3) LOADQ(it * 128 + 128);
        MFMA_STEP();
        __syncthreads();
        *(uint4*)&lA[srow * LAS2 + skof]     = ra0;
        *(uint4*)&lA[srow * LAS2 + skof + 8] = ra1;
        *(uint4*)&lB[srow * LAS2 + skof]     = rb0;
        *(uint4*)&lB[srow * LAS2 + skof + 8] = rb1;
        __syncthreads();
        if (it < 3) LOADR(it * 128 + 192);
        MFMA_STEP();
    }
    #undef LOADQ
    #undef LOADR
    #undef MFMA_STEP

    const f32x4* accs[4] = { &acc00, &acc01, &acc10, &acc11 };
    #pragma unroll
    for (int i = 0; i < 2; ++i) {
        #pragma unroll
        for (int j = 0; j < 2; ++j) {
            const f32x4& a = *accs[i * 2 + j];
            #pragma unroll
            for (int r = 0; r < 4; ++r) {
                int m = m0 + wm * 32 + i * 16 + quad * 4 + r;
                int n = n0 + wn * 32 + j * 16 + l16;
                float v = a[r];
                if (mode == 0)
                    ept[(long long)zz * 262144 + (long long)m * 512 + n] =
                        f2b(__builtin_amdgcn_exp2f(C2 * v));
                else if (mode == 1)
                    hp[(long long)m * 512 + n] = C2 * (v + battn[n]);
                else
                    hh[(long long)m * 512 + n] = v;
            }
        }
    }
}

// =============== wave/block reductions ======================================
__device__ inline float wred_sum(float v) {
    #pragma unroll
    for (int i = 32; i > 0; i >>= 1) v += __shfl_xor(v, i);
    return v;
}
__device__ inline void bred2_max(float v0, float v1, float* red, int tid,
                                 float* o0, float* o1) {
    #pragma unroll
    for (int i = 32; i > 0; i >>= 1) {
        v0 = fmaxf(v0, __shfl_xor(v0, i));
        v1 = fmaxf(v1, __shfl_xor(v1, i));
    }
    __syncthreads();
    if ((tid & 63) == 0) { red[tid >> 6] = v0; red[8 + (tid >> 6)] = v1; }
    __syncthreads();
    float a0 = red[0], a1 = red[8];
    #pragma unroll
    for (int i = 1; i < 8; ++i) { a0 = fmaxf(a0, red[i]); a1 = fmaxf(a1, red[8 + i]); }
    *o0 = a0; *o1 = a1;
}
__device__ inline void bred2_sum(float v0, float v1, float* red, int tid,
                                 float* o0, float* o1) {
    #pragma unroll
    for (int i = 32; i > 0; i >>= 1) { v0 += __shfl_xor(v0, i); v1 += __shfl_xor(v1, i); }
    __syncthreads();
    if ((tid & 63) == 0) { red[tid >> 6] = v0; red[8 + (tid >> 6)] = v1; }
    __syncthreads();
    float a0 = 0.f, a1 = 0.f;
    #pragma unroll
    for (int i = 0; i < 8; ++i) { a0 += red[i]; a1 += red[8 + i]; }
    *o0 = a0; *o1 = a1;
}

// =============== energies + masked softmax + wc (fused, dual-t) ==============
// r13 structure + FOUR-DEEP prefetch rings in both heavy loops: the 2-deep
// ring issued loads only ~1 iteration (~256 SIMD-cyc at 4 waves/SIMD) ahead
// of use -- marginal vs ~200-300cyc L2 latency (VALUBusy stuck at 62%).
// 4-deep = 2 proc8p units (~512 SIMD-cyc) of cover. +8 VGPR per loop.
__device__ inline void proc8p(uint4 c0, uint4 c1, float4 hw0, float4 hw1,
                              float* a0, float* a1) {
    u32 p[4] = {c0.x, c0.y, c0.z, c0.w};
    u32 q[4] = {c1.x, c1.y, c1.z, c1.w};
    #pragma unroll
    for (int i = 0; i < 4; ++i) {
        float x0l = __uint_as_float(p[i] << 16);
        float x0h = __uint_as_float(p[i] & 0xFFFF0000u);
        float x1l = __uint_as_float(q[i] << 16);
        float x1h = __uint_as_float(q[i] & 0xFFFF0000u);
        float A, B, num;
        A = fmaf(hw0.x, x0l, 1.f);
        B = fmaf(hw1.x, x1l, 1.f);
        num = fmaf(hw0.z, B, hw1.z * A);
        a0[2*i]   = fmaf(num, __builtin_amdgcn_rcpf(A * B), a0[2*i]);
        A = fmaf(hw0.x, x0h, 1.f);
        B = fmaf(hw1.x, x1h, 1.f);
        num = fmaf(hw0.z, B, hw1.z * A);
        a0[2*i+1] = fmaf(num, __builtin_amdgcn_rcpf(A * B), a0[2*i+1]);
        A = fmaf(hw0.y, x0l, 1.f);
        B = fmaf(hw1.y, x1l, 1.f);
        num = fmaf(hw0.z, B, hw1.z * A);
        a1[2*i]   = fmaf(num, __builtin_amdgcn_rcpf(A * B), a1[2*i]);
        A = fmaf(hw0.y, x0h, 1.f);
        B = fmaf(hw1.y, x1h, 1.f);
        num = fmaf(hw0.z, B, hw1.z * A);
        a1[2*i+1] = fmaf(num, __builtin_amdgcn_rcpf(A * B), a1[2*i+1]);
    }
}
__device__ inline void wcproc2(uint4 c, float2 ap, float* acc0, float* acc1) {
    u32 cc[4] = {c.x, c.y, c.z, c.w};
    #pragma unroll
    for (int i = 0; i < 4; ++i) {
        float el = __uint_as_float(cc[i] << 16);
        float eh = __uint_as_float(cc[i] & 0xFFFF0000u);
        acc0[2*i]   = fmaf(ap.x, el, acc0[2*i]);
        acc0[2*i+1] = fmaf(ap.x, eh, acc0[2*i+1]);
        acc1[2*i]   = fmaf(ap.y, el, acc1[2*i]);
        acc1[2*i+1] = fmaf(ap.y, eh, acc1[2*i+1]);
    }
}

__global__ __launch_bounds__(512) void energies(
    const float* __restrict__ maskp, const float* __restrict__ hp,
    const u16* __restrict__ ept, const float* __restrict__ Wv,
    const float* __restrict__ bvp, const u16* __restrict__ enc_bf,
    float* __restrict__ attn, float* __restrict__ wc)
{
    __shared__ __align__(16) float4 hpw[512];   // (e^{2hp_t0}, e^{2hp_t1}, Wv, -) 8KB
    __shared__ float pa[2][8][512];             // 32KB partials, single pass; wc reuse
    __shared__ float aL[512][2];                // 4KB attn weights for wc
    __shared__ float red[16];
    const int tid = threadIdx.x;
    const int b  = blockIdx.x & 7;              // XCD-grouped
    const int t0 = (blockIdx.x >> 3) * 2;
    const long long row0 = (long long)(b * 128 + t0) * 512;

    // ---- setup: hpw (both t rows) + sumWv ----
    float hv0 = hp[row0 + tid];
    float hv1 = hp[row0 + 512 + tid];
    float w = Wv[tid];
    hpw[tid] = make_float4(__builtin_amdgcn_exp2f(hv0),
                           __builtin_amdgcn_exp2f(hv1), w, 0.f);
    float wsum = wred_sum(w);
    if ((tid & 63) == 0) red[tid >> 6] = wsum;
    __syncthreads();                            // hpw + red visible
    float sumWv = 0.f;
    #pragma unroll
    for (int i = 0; i < 8; ++i) sumWv += red[i];

    // ---- main loop: wave kg owns 64 k-rows; thread: 8 s-cols, both t ----
    const int kg = tid >> 6, sl = tid & 63;
    const int s0 = sl * 8;
    const u16* eb = ept + (long long)b * 262144 + (kg * 64) * 512 + s0;
    const float4* hq = &hpw[kg * 64];

    float a0[8] = {0,0,0,0,0,0,0,0}, a1[8] = {0,0,0,0,0,0,0,0};
    uint4 c0 = *(const uint4*)(eb);
    uint4 c1 = *(const uint4*)(eb + 512);
    uint4 c2 = *(const uint4*)(eb + 1024);
    uint4 c3 = *(const uint4*)(eb + 1536);
    for (int kk = 0; kk < 60; kk += 2) {
        const u16* nb = eb + (long long)(kk + 4) * 512;
        uint4 n0 = *(const uint4*)(nb);
        uint4 n1 = *(const uint4*)(nb + 512);
        proc8p(c0, c1, hq[kk], hq[kk + 1], a0, a1);
        c0 = c2; c1 = c3; c2 = n0; c3 = n1;
    }
    proc8p(c0, c1, hq[60], hq[61], a0, a1);
    proc8p(c2, c3, hq[62], hq[63], a0, a1);

    // ---- single-pass cross-wave reduction through 32KB pa ----
    *(float4*)&pa[0][kg][s0]     = make_float4(a0[0], a0[1], a0[2], a0[3]);
    *(float4*)&pa[0][kg][s0 + 4] = make_float4(a0[4], a0[5], a0[6], a0[7]);
    *(float4*)&pa[1][kg][s0]     = make_float4(a1[0], a1[1], a1[2], a1[3]);
    *(float4*)&pa[1][kg][s0 + 4] = make_float4(a1[4], a1[5], a1[6], a1[7]);
    __syncthreads();
    float A0 = 0.f, A1 = 0.f;
    #pragma unroll
    for (int g = 0; g < 8; ++g) { A0 += pa[0][g][tid]; A1 += pa[1][g][tid]; }

    // ---- softmax: thread owns s = tid, both t-rows ----
    const int s = tid;
    float mv = maskp[(long long)b * 512 + s];
    float bv0 = bvp[0];
    float r0 = (bv0 + sumWv - 2.f * A0) * mv; r0 *= mv;
    float r1 = (bv0 + sumWv - 2.f * A1) * mv; r1 *= mv;

    float mx0, mx1;
    bred2_max(r0, r1, red, tid, &mx0, &mx1);
    float ex0 = __builtin_amdgcn_exp2f((r0 - mx0) * LOG2E) * mv;
    float ex1 = __builtin_amdgcn_exp2f((r1 - mx1) * LOG2E) * mv;
    float sm0, sm1;
    bred2_sum(ex0, ex1, red, tid, &sm0, &sm1);
    float at0 = ex0 * (1.f / (sm0 + 1e-6f));
    float at1 = ex1 * (1.f / (sm1 + 1e-6f));
    attn[row0 + s]       = at0;
    attn[row0 + 512 + s] = at1;
    aL[s][0] = at0; aL[s][1] = at1;
    __syncthreads();                            // aL visible; pa free for reuse

    // ---- wc = attn @ enc: thread owns 8 e-cols (eg) x 64 s-rows (sg) ----
    const int eg = tid & 63, sg = tid >> 6;
    const u16* encb = enc_bf + (long long)b * 262144 + (long long)(sg * 64) * 512 + eg * 8;
    const float2* aq = (const float2*)&aL[sg * 64][0];
    float acc0[8] = {0,0,0,0,0,0,0,0}, acc1[8] = {0,0,0,0,0,0,0,0};
    uint4 e0 = *(const uint4*)(encb);
    uint4 e1 = *(const uint4*)(encb + 512);
    uint4 e2 = *(const uint4*)(encb + 1024);
    uint4 e3 = *(const uint4*)(encb + 1536);
    for (int j = 0; j < 60; j += 2) {
        const u16* nb = encb + (long long)(j + 4) * 512;
        uint4 f0 = *(const uint4*)(nb);
        uint4 f1 = *(const uint4*)(nb + 512);
        wcproc2(e0, aq[j],     acc0, acc1);
        wcproc2(e1, aq[j + 1], acc0, acc1);
        e0 = e2; e1 = e3; e2 = f0; e3 = f1;
    }
    wcproc2(e0, aq[60], acc0, acc1);
    wcproc2(e1, aq[61], acc0, acc1);
    wcproc2(e2, aq[62], acc0, acc1);
    wcproc2(e3, aq[63], acc0, acc1);

    // ---- single-pass wc reduction through pa ----
    *(float4*)&pa[0][sg][eg * 8]     = make_float4(acc0[0], acc0[1], acc0[2], acc0[3]);
    *(float4*)&pa[0][sg][eg * 8 + 4] = make_float4(acc0[4], acc0[5], acc0[6], acc0[7]);
    *(float4*)&pa[1][sg][eg * 8]     = make_float4(acc1[0], acc1[1], acc1[2], acc1[3]);
    *(float4*)&pa[1][sg][eg * 8 + 4] = make_float4(acc1[4], acc1[5], acc1[6], acc1[7]);
    __syncthreads();
    float wcv0 = 0.f, wcv1 = 0.f;
    #pragma unroll
    for (int g = 0; g < 8; ++g) { wcv0 += pa[0][g][tid]; wcv1 += pa[1][g][tid]; }
    wc[row0 + tid]       = wcv0;
    wc[row0 + 512 + tid] = wcv1;
}

// =============== hout: h_tilde = tanh(wc @ Wout[:,:512]^T + hh) ==============
__global__ __launch_bounds__(256) void hout_k(
    const float* __restrict__ wc, const u16* __restrict__ Wout_bf,
    float* __restrict__ out)
{
    __shared__ u16 lA[32 * LAS];
    __shared__ u16 lB[64 * LAS];
    const int tid = threadIdx.x;
    const int wvi = tid >> 6, ln = tid & 63;
    const int l16 = ln & 15, quad = ln >> 4;
    const int msub = wvi & 1, npair = wvi >> 1;
    const int m0 = blockIdx.y * 32, n0 = blockIdx.x * 64;
    const int rowA = tid >> 3, kofA = (tid & 7) * 4;
    const int rowB = tid >> 2, kofB = (tid & 3) * 8;
    f32x4 acc0 = {0,0,0,0}, acc1 = {0,0,0,0};

    for (int k0 = 0; k0 < 512; k0 += 32) {
        float4 av = *(const float4*)(wc + (long long)(m0 + rowA) * 512 + k0 + kofA);
        uint4 bv = *(const uint4*)(Wout_bf + (long long)(n0 + rowB) * 1024 + k0 + kofB);
        __syncthreads();
        *(uint2*)&lA[rowA * LAS + kofA] = make_uint2(pkcvt(av.x, av.y), pkcvt(av.z, av.w));
        int kk = kofB ^ (((rowB >> 3) & 3) << 3);
        *(uint4*)&lB[rowB * LAS + kk] = bv;
        __syncthreads();
        bf16x8 a = *(const bf16x8*)&lA[(msub * 16 + l16) * LAS + quad * 8];
        int nr0 = npair * 32 + l16, nr1 = nr0 + 16;
        bf16x8 b0 = *(const bf16x8*)&lB[nr0 * LAS + (quad * 8 ^ (((nr0 >> 3) & 3) << 3))];
        bf16x8 b1 = *(const bf16x8*)&lB[nr1 * LAS + (quad * 8 ^ (((nr1 >> 3) & 3) << 3))];
        acc0 = __builtin_amdgcn_mfma_f32_16x16x32_bf16(a, b0, acc0, 0, 0, 0);
        acc1 = __builtin_amdgcn_mfma_f32_16x16x32_bf16(a, b1, acc1, 0, 0, 0);
    }
    #pragma unroll
    for (int j = 0; j < 2; ++j) {
        const f32x4& a = j ? acc1 : acc0;
        #pragma unroll
        for (int r = 0; r < 4; ++r) {
            int m = m0 + msub * 16 + quad * 4 + r;
            int n = n0 + npair * 32 + j * 16 + l16;
            long long idx = (long long)m * 512 + n;
            out[idx] = tanh_fast(a[r] + out[idx]);   // out[idx] holds hh
        }
    }
}

extern "C" void kernel_launch(void* const* d_in, const int* in_sizes, int n_in,
                              void* d_out, int out_size, void* d_ws, size_t ws_size,
                              hipStream_t stream)
{
    const float* hidden = (const float*)d_in[0];  // (8,128,512)
    const float* enc    = (const float*)d_in[1];  // (8,512,512)
    const float* mask   = (const float*)d_in[2];  // (8,512)
    const float* Wattn  = (const float*)d_in[3];  // (512,1024)
    const float* battn  = (const float*)d_in[4];  // (512,)
    const float* Wv     = (const float*)d_in[5];  // (512,)
    const float* bvp    = (const float*)d_in[6];  // (1,)
    const float* Wout   = (const float*)d_in[7];  // (512,1024)
    float* out = (float*)d_out;

    float* hp  = (float*)d_ws;                      // @0   2MB fp32
    u16*   ept = (u16*)((char*)d_ws + (2 << 20));   // @2M  4MB bf16 (exp2 domain)
    u16*   bfp = (u16*)((char*)d_ws + (6 << 20));   // @6M  7MB bf16 pool
    u16* enc_bf    = bfp;                // 2M elems
    u16* hidden_bf = bfp + 2097152;      // 512K
    u16* Wattn_bf  = bfp + 2621440;      // 512K
    u16* Wout_bf   = bfp + 3145728;      // 512K

    tobf<<<1792, 256, 0, stream>>>(enc, hidden, Wattn, Wout, bfp);
    proj<<<768, 256, 0, stream>>>(hidden_bf, enc_bf, Wattn_bf, battn, Wout_bf,
                                  hp, ept, out /* hh in-place */);
    energies<<<512, 512, 0, stream>>>(mask, hp, ept, Wv, bvp, enc_bf,
                                      out + OUT_ATTN, out + OUT_WC);
    hout_k<<<dim3(8, 32, 1), 256, 0, stream>>>(out + OUT_WC, Wout_bf, out);
}